// Round 5
// baseline (1610.525 us; speedup 1.0000x reference)
//
#include <hip/hip_runtime.h>
#include <math.h>

// ---------------- workspace layout (float2 units) ----------------
// ws_bs : 24 gates x 384  sector-packed BS: for sector N (size s, row SR=even(s)),
//                         g[SECBASE[N] + o*SR + ti] = U[j_o][k_ti]
// ws_g1 : 16 gates x 64   one-mode GT[k*8+j] with rotation/Kerr diagonals folded
#define WS_G1_OFF   (24*384)

typedef float v2f __attribute__((ext_vector_type(2)));

// complex MAC: acc += s*g  via 2x v_pk_fma_f32 (all-VGPR operands)
__device__ __forceinline__ void cmac(v2f& acc, v2f s, v2f g){
  asm("v_pk_fma_f32 %0, %1, %2, %0 op_sel_hi:[0,1,1]\n\t"
      "v_pk_fma_f32 %0, %1, %2, %0 op_sel:[1,1,0] op_sel_hi:[1,0,1] neg_lo:[1,0,0]"
      : "+v"(acc) : "v"(s), "v"(g));
}

// Force a pointer into VGPRs: breaks scalar-uniformity proof, so gate loads
// become global_load_dwordx2 (VGPR dest, imm offset) instead of s_load+v_mov.
__device__ __forceinline__ const float2* vptr(const float2* p){
  asm("" : "+v"(p));
  return p;
}

// state LDS swizzle: phys = idx ^ ((idx>>6)&15)  (bijective, no padding, 32768 B)
__device__ __forceinline__ int SW(int idx){ return idx ^ ((idx>>6)&15); }

// ---------------- setup: 24 beamsplitter 64x64 expm ----------------
__global__ __launch_bounds__(256) void setup_bs(
    const float* __restrict__ th1, const float* __restrict__ ph1,
    const float* __restrict__ th2, const float* __restrict__ ph2,
    float2* __restrict__ ws)
{
  __shared__ float2 bufA[4096];
  __shared__ float2 bufB[4096];
  const int g = blockIdx.x;          // 0..23
  const int t = threadIdx.x;
  const int l = g/12, intf = (g%12)/6, pos = g%6;
  const float th = (intf ? th2 : th1)[l*6+pos];
  const float ph = (intf ? ph2 : ph1)[l*6+pos];
  float nrm = fabsf(th)*14.0f;                 // row-sum norm bound
  int sq = 0;
  if (nrm > 0.25f) sq = (int)ceilf(log2f(nrm*4.0f));
  const float tc  = th * ldexpf(1.0f, -sq);    // scaled theta
  const float cph = cosf(ph), sph = sinf(ph);

  float2* cur = bufA; float2* nxt = bufB;
  for (int e=0;e<16;e++){ int idx=t*16+e;
    cur[idx] = make_float2(((idx>>6)==(idx&63))?1.f:0.f, 0.f); }
  __syncthreads();
  // Horner Taylor: B = I + Hs*B/k, k=12..1   (Hs applied sparsely: 2 taps/row)
  for (int k=12;k>=1;k--){
    const float inv = 1.0f/(float)k;
    for (int e=0;e<16;e++){
      const int idx=t*16+e; const int row=idx>>6, c=idx&63;
      const int m1=row>>3, m2=row&7;
      float vx=0.f, vy=0.f;
      if (m1<7 && m2>=1){
        const float mag = tc*sqrtf((float)((m1+1)*m2));
        const float2 q = cur[((m1+1)*8+(m2-1))*64 + c];
        vx += mag*(cph*q.x - sph*q.y);
        vy += mag*(cph*q.y + sph*q.x);
      }
      if (m1>=1 && m2<7){
        const float mag = tc*sqrtf((float)(m1*(m2+1)));
        const float2 q = cur[((m1-1)*8+(m2+1))*64 + c];
        vx -= mag*(cph*q.x + sph*q.y);
        vy -= mag*(cph*q.y - sph*q.x);
      }
      vx *= inv; vy *= inv;
      if (row==c) vx += 1.0f;
      nxt[idx] = make_float2(vx,vy);
    }
    __syncthreads();
    float2* tmp=cur; cur=nxt; nxt=tmp;
  }
  // squarings
  for (int si=0; si<sq; si++){
    for (int e=0;e<16;e++){
      const int idx=t*16+e; const int row=idx>>6, c=idx&63;
      float vx=0.f, vy=0.f;
      for (int q=0;q<64;q++){
        const float2 a_ = cur[row*64+q];
        const float2 b_ = cur[q*64+c];
        vx += a_.x*b_.x - a_.y*b_.y;
        vy += a_.x*b_.y + a_.y*b_.x;
      }
      nxt[idx] = make_float2(vx,vy);
    }
    __syncthreads();
    float2* tmp=cur; cur=nxt; nxt=tmp;
  }
  // sector-packed write: enumerate (N, o, ti-with-row-pad) linearly over 384 slots
  for (int e=t; e<384; e+=256){
    int rem = e, N = 0, S_=0, SR_=0;
    for (; N<15; N++){
      S_  = 8 - ((N<7)?(7-N):(N-7));
      SR_ = (S_+1)&~1;
      if (rem < S_*SR_) break;
      rem -= S_*SR_;
    }
    float2 v = make_float2(0.f,0.f);
    if (N < 15){
      const int o = rem / SR_, ti = rem % SR_;
      if (ti < S_){
        const int T0 = (N>7)?(N-7):0;
        const int j = 7*(T0+o)+N, k = 7*(T0+ti)+N;
        v = cur[j*64 + k];
      }
    }
    ws[g*384 + e] = v;
  }
}

// ---------------- setup: 16 one-mode 8x8 expm, diagonals folded in ----------------
__global__ __launch_bounds__(128) void setup_small(
    const float* __restrict__ rr,  const float* __restrict__ phr,
    const float* __restrict__ aa,  const float* __restrict__ pha,
    const float* __restrict__ vph1,const float* __restrict__ vph2,
    const float* __restrict__ kap,
    float2* __restrict__ ws_g1)
{
  const int g = blockIdx.x, t = threadIdx.x;   // g: 0..15
  __shared__ float2 h8[64], bufA[64], bufB[64];
  const int isSq = (g < 8);
  const int gi = isSq ? g : (g-8);
  const int li = gi>>2, m = gi&3;
  const float p1 = isSq ? rr[li*4+m]  : aa[li*4+m];
  const float p2 = isSq ? phr[li*4+m] : pha[li*4+m];
  const float nrm = fabsf(p1)*6.0f;
  int sq = 0; if (nrm > 0.25f) sq = (int)ceilf(log2f(nrm*4.0f));
  const float sc = ldexpf(1.0f,-sq);
  const float cp = cosf(p2), sp = sinf(p2);
  if (t < 64){
    const int row=t>>3, c=t&7;
    float2 v = make_float2(0.f,0.f);
    if (isSq){
      if (c == row+2){ const float mg = 0.5f*p1*sqrtf((float)((row+1)*(row+2)));
                       v = make_float2( mg*cp, -mg*sp); }
      else if (c+2 == row){ const float mg = 0.5f*p1*sqrtf((float)((row-1)*row));
                       v = make_float2(-mg*cp, -mg*sp); }
    } else {
      if (c+1 == row){ const float mg = p1*sqrtf((float)row);
                       v = make_float2( mg*cp,  mg*sp); }
      else if (c == row+1){ const float mg = p1*sqrtf((float)(row+1));
                       v = make_float2(-mg*cp,  mg*sp); }
    }
    h8[t]   = make_float2(v.x*sc, v.y*sc);
    bufA[t] = make_float2((row==c)?1.f:0.f, 0.f);
  }
  __syncthreads();
  float2* cur=bufA; float2* nxt=bufB;
  for (int k=12;k>=1;k--){
    const float inv = 1.0f/(float)k;
    if (t<64){
      const int row=t>>3, c=t&7;
      float vx=0.f, vy=0.f;
      for (int q=0;q<8;q++){
        const float2 a_=h8[row*8+q], b_=cur[q*8+c];
        vx += a_.x*b_.x - a_.y*b_.y; vy += a_.x*b_.y + a_.y*b_.x;
      }
      vx*=inv; vy*=inv; if (row==c) vx += 1.f;
      nxt[t]=make_float2(vx,vy);
    }
    __syncthreads();
    float2* tmp=cur; cur=nxt; nxt=tmp;
  }
  for (int si=0; si<sq; si++){
    if (t<64){
      const int row=t>>3, c=t&7;
      float vx=0.f, vy=0.f;
      for (int q=0;q<8;q++){
        const float2 a_=cur[row*8+q], b_=cur[q*8+c];
        vx += a_.x*b_.x - a_.y*b_.y; vy += a_.x*b_.y + a_.y*b_.x;
      }
      nxt[t]=make_float2(vx,vy);
    }
    __syncthreads();
    float2* tmp=cur; cur=nxt; nxt=tmp;
  }
  if (t<64){
    const int kk=t>>3, j=t&7;
    const float2 v = cur[j*8+kk];          // G[j][kk]
    float ang;
    if (isSq) ang = vph1[li*4+m]*(float)kk;
    else      ang = vph2[li*4+m]*(float)kk + kap[li*4+m]*(float)(j*j);
    const float ca = cosf(ang), sa = sinf(ang);
    ws_g1[g*64 + t] = make_float2(v.x*ca - v.y*sa, v.x*sa + v.y*ca);  // GT[k][j]
  }
}

// ---------------- main kernel ----------------
// State LDS, XOR-swizzled (no padding): phys = idx ^ ((idx>>6)&15).
// Logical strides i0:512 i1:64 i2:8 i3:1.
// bs_gate: lane = spectator; each wave owns disjoint photon-number sectors.
// Gates arrive via VGPR-pointer global loads (imm offsets, VMEM pipe, 0 VALU).

template<int NN,int PM>
__device__ __forceinline__ void bs_sector(const float2* __restrict__ gsec,
                                          float2* __restrict__ Sm,
                                          int lane, int A1, int X1, int B2, int C2)
{
  constexpr int S_ = 8 - ((NN<7)?(7-NN):(NN-7));
  constexpr int T0 = (NN>7)?(NN-7):0;
  constexpr int SR = (S_+1)&~1;
  int ka[S_];
  v2f sv[S_];
#pragma unroll
  for (int i=0;i<S_;i++){
    const int k = 7*(T0+i)+NN;
    int addr;
    if constexpr (PM==0)      addr = (lane ^ (k&15)) + 512*(k>>3) + 64*(k&7);
    else if constexpr (PM==1) addr = (A1 + 64*(k>>3) + 8*(k&7)) ^ ((k>>3) ^ X1);
    else                      addr = B2 + ((8*(k>>3) + (k&7)) ^ C2);
    ka[i] = addr;
    sv[i] = *(const v2f*)&Sm[addr];
  }
#pragma unroll
  for (int o=0;o<S_;o++){
    v2f acc = (v2f){0.f,0.f};
#pragma unroll
    for (int i=0;i<S_;i++){
      const v2f g = *(const v2f*)&gsec[o*SR+i];   // global_load_dwordx2, imm offset
      cmac(acc, sv[i], g);
    }
    *(v2f*)&Sm[ka[o]] = acc;
  }
}

template<int PM>
__device__ __forceinline__ void bs_gate(const float2* __restrict__ gb_in,
                                        float2* __restrict__ Sm,
                                        int lane, int A1, int X1, int B2, int C2,
                                        int wvu)
{
  const float2* gb = vptr(gb_in);     // VGPR base -> vector loads w/ imm offsets
  // per-wave sector lists, cmac-balanced: 85 / 84 / 87 / 88
  if (wvu==0){
    bs_sector<7 ,PM>(gb+156, Sm, lane,A1,X1,B2,C2);
    bs_sector<3 ,PM>(gb+18,  Sm, lane,A1,X1,B2,C2);
    bs_sector<13,PM>(gb+370, Sm, lane,A1,X1,B2,C2);
    bs_sector<0 ,PM>(gb+0,   Sm, lane,A1,X1,B2,C2);
  } else if (wvu==1){
    bs_sector<6 ,PM>(gb+100, Sm, lane,A1,X1,B2,C2);
    bs_sector<4 ,PM>(gb+34,  Sm, lane,A1,X1,B2,C2);
    bs_sector<2 ,PM>(gb+6,   Sm, lane,A1,X1,B2,C2);
    bs_sector<14,PM>(gb+374, Sm, lane,A1,X1,B2,C2);
  } else if (wvu==2){
    bs_sector<8 ,PM>(gb+220, Sm, lane,A1,X1,B2,C2);
    bs_sector<10,PM>(gb+312, Sm, lane,A1,X1,B2,C2);
    bs_sector<12,PM>(gb+358, Sm, lane,A1,X1,B2,C2);
    bs_sector<1 ,PM>(gb+2,   Sm, lane,A1,X1,B2,C2);
  } else {
    bs_sector<5 ,PM>(gb+64,  Sm, lane,A1,X1,B2,C2);
    bs_sector<9 ,PM>(gb+276, Sm, lane,A1,X1,B2,C2);
    bs_sector<11,PM>(gb+342, Sm, lane,A1,X1,B2,C2);
  }
  __syncthreads();
}

// one-mode gate on mode M; swizzled per-tap addresses, gates via VGPR-ptr loads.
template<int M>
__device__ __forceinline__ void one_mode(const float2* __restrict__ gb_in,
                                         float2* __restrict__ Sm, int t)
{
  const float2* gb = vptr(gb_in);
  int ad[2][8];
#pragma unroll
  for (int vv=0; vv<2; vv++){
    const int v = t + vv*256;
    if constexpr (M==0){
      const int i1=(v>>6)&7;
      const int P = 64*i1 + ((v&63) ^ i1);
      const int P8 = P ^ 8;
#pragma unroll
      for (int k=0;k<8;k++) ad[vv][k] = ((k&1)?P8:P) + 512*k;
    } else if constexpr (M==1){
      const int i0=(v>>6)&7;
      const int P = 512*i0 + ((v&63) ^ ((i0&1)<<3));
#pragma unroll
      for (int k=0;k<8;k++) ad[vv][k] = (P ^ (k&7)) + 64*k;
    } else if constexpr (M==2){
      const int i0=((v>>3)&1)|(((v>>7)&3)<<1);
      const int i1=(v>>4)&7, i3=v&7;
      const int P = 512*i0 + 64*i1 + (i3 ^ i1);
      const int X8 = (i0&1)<<3;
#pragma unroll
      for (int k=0;k<8;k++) ad[vv][k] = P + ((8*k) ^ X8);
    } else {
      const int i0=(v>>4)&7, i1=v&7;
      const int i2=((v>>3)&1)|(((v>>7)&3)<<1);
      const int P = 512*i0 + 64*i1 + ((8*i2) ^ ((i0&1)<<3));
#pragma unroll
      for (int k=0;k<8;k++) ad[vv][k] = P + (k ^ i1);
    }
  }
  v2f acc[2][8];
#pragma unroll
  for (int vv=0; vv<2; vv++)
#pragma unroll
    for (int j=0;j<8;j++) acc[vv][j] = (v2f){0.f,0.f};
#pragma unroll
  for (int k=0;k<8;k++){
    const v2f sA = *(const v2f*)&Sm[ad[0][k]];
    const v2f sB = *(const v2f*)&Sm[ad[1][k]];
#pragma unroll
    for (int j=0;j<8;j++){
      const v2f g = *(const v2f*)&gb[k*8+j];      // global_load_dwordx2, imm offset
      cmac(acc[0][j], sA, g);
      cmac(acc[1][j], sB, g);
    }
  }
#pragma unroll
  for (int vv=0; vv<2; vv++)
#pragma unroll
    for (int j=0;j<8;j++) *(v2f*)&Sm[ad[vv][j]] = acc[vv][j];
  __syncthreads();
}

__global__ __launch_bounds__(256,4) void qnn_main(
    const float* __restrict__ x, const float2* __restrict__ ws,
    float* __restrict__ out)
{
  __shared__ __align__(16) float2 S[4096];       // exactly 32 KiB
  const int b = blockIdx.x, t = threadIdx.x;
  const int lane = t & 63;
  const int wvu = __builtin_amdgcn_readfirstlane(t>>6);
  const int i2c = (lane>>3)&7, i3c = lane&7;

  // coherent amplitudes c_n = e^{-x^2/2} x^n / sqrt(n!)  -- per-wave, via shuffles
  float c0[8]; float c1a, c1b, c23;
  {
    const float x0=x[b*4+0], x1=x[b*4+1], x2=x[b*4+2], x3=x[b*4+3];
    const int m=(lane>>3)&3;
    const float xv = (m&2)?((m&1)?x3:x2):((m&1)?x1:x0);
    float val = expf(-0.5f*xv*xv);
    const int n = lane&7;
#pragma unroll
    for (int q=1;q<8;q++) if (q<=n) val *= xv*rsqrtf((float)q);
    c23 = __shfl(val,16+i2c,64)*__shfl(val,24+i3c,64);
    c1a = __shfl(val,8+wvu,64); c1b = __shfl(val,12+wvu,64);
#pragma unroll
    for (int h=0;h<8;h++) c0[h] = __shfl(val,h,64);
  }
#pragma unroll
  for (int e=0;e<16;e++){
    const int idx = e*256 + t;
    S[SW(idx)] = make_float2(c0[e>>1]*((e&1)?c1b:c1a)*c23, 0.f);
  }
  __syncthreads();

  // per-lane spectator constants for the bs pair maps
  const int A1 = 512*(lane>>3) + (lane&7);           // PM1: spect (i0,i3)
  const int X1 = ((lane>>3)&1)<<3;
  const int B2 = 512*(lane>>3) + 64*(lane&7);        // PM2: spect (i0,i1)
  const int C2 = (lane&7) | (((lane>>3)&1)<<3);

  const float2* ws_g1 = ws + WS_G1_OFF;
#pragma unroll 1
  for (int seg=0; seg<4; seg++){                     // seg = l*2 + r
    const float2* bsg = ws + seg*(6*384);
#pragma unroll 1
    for (int q=0; q<6; q++){                         // pair pattern (0,1),(2,3),(1,2) x2
      const float2* gq = bsg + q*384;
      const int pm = (q>=3)?(q-3):q;
      if (pm==0)      bs_gate<0>(gq, S, lane,A1,X1,B2,C2, wvu);
      else if (pm==1) bs_gate<2>(gq, S, lane,A1,X1,B2,C2, wvu);
      else            bs_gate<1>(gq, S, lane,A1,X1,B2,C2, wvu);
    }
    const int l = seg>>1, r = seg&1;
    const float2* om = ws_g1 + (r*8 + l*4)*64;       // r=0: squeeze', r=1: disp'
    one_mode<0>(om,     S, t);
    one_mode<1>(om+64,  S, t);
    one_mode<2>(om+128, S, t);
    one_mode<3>(om+192, S, t);
  }

  // <X_i> = 2 Re sum conj(s[n_i]) sqrt(n_i+1) s[n_i+1]
  const float w1a = sqrtf((float)(wvu+1));
  const float w1b = sqrtf((float)(wvu+5));
  const float w2 = sqrtf((float)(i2c+1)), w3 = sqrtf((float)(i3c+1));
  float am0=0.f, am1=0.f, am2=0.f, am3=0.f;
#pragma unroll
  for (int e=0;e<16;e++){
    const int idx = e*256 + t;
    const float2 a = S[SW(idx)];
    if ((e>>1) < 7){
      const float2 bz = S[SW(idx+512)];
      am0 = fmaf(a.x*bz.x + a.y*bz.y, sqrtf((float)((e>>1)+1)), am0);
    }
    if (((e&1)==0) || (wvu<3)){          // i1 = wvu + 4*(e&1)
      const float2 bz = S[SW(idx+64)];
      am1 = fmaf(a.x*bz.x + a.y*bz.y, (e&1)?w1b:w1a, am1);
    }
    if (i2c < 7){
      const float2 bz = S[SW(idx+8)];
      am2 = fmaf(a.x*bz.x + a.y*bz.y, w2, am2);
    }
    if (i3c < 7){
      const float2 bz = S[SW(idx+1)];
      am3 = fmaf(a.x*bz.x + a.y*bz.y, w3, am3);
    }
  }
#pragma unroll
  for (int o=32;o;o>>=1){
    am0 += __shfl_down(am0,o,64);
    am1 += __shfl_down(am1,o,64);
    am2 += __shfl_down(am2,o,64);
    am3 += __shfl_down(am3,o,64);
  }
  __syncthreads();                       // all state reads done before red reuses S
  float* red = (float*)S;
  if ((t&63)==0){
    red[wvu*4+0]=am0; red[wvu*4+1]=am1; red[wvu*4+2]=am2; red[wvu*4+3]=am3;
  }
  __syncthreads();
  if (t<4) out[b*4+t] = 2.f*(red[t]+red[4+t]+red[8+t]+red[12+t]);
}

// ---------------- host ----------------
extern "C" void kernel_launch(void* const* d_in, const int* in_sizes, int n_in,
                              void* d_out, int out_size, void* d_ws, size_t ws_size,
                              hipStream_t stream)
{
  const float* x    = (const float*)d_in[0];
  const float* th1  = (const float*)d_in[1];
  const float* ph1  = (const float*)d_in[2];
  const float* vph1 = (const float*)d_in[3];
  const float* rr   = (const float*)d_in[4];
  const float* phr  = (const float*)d_in[5];
  const float* th2  = (const float*)d_in[6];
  const float* ph2  = (const float*)d_in[7];
  const float* vph2 = (const float*)d_in[8];
  const float* aa   = (const float*)d_in[9];
  const float* pha  = (const float*)d_in[10];
  const float* kap  = (const float*)d_in[11];
  float2* ws  = (float2*)d_ws;
  float*  out = (float*)d_out;
  const int B = in_sizes[0] / 4;

  hipLaunchKernelGGL(setup_bs, dim3(24), dim3(256), 0, stream, th1, ph1, th2, ph2, ws);
  hipLaunchKernelGGL(setup_small, dim3(16), dim3(128), 0, stream,
                     rr, phr, aa, pha, vph1, vph2, kap, ws + WS_G1_OFF);
  hipLaunchKernelGGL(qnn_main, dim3(B), dim3(256), 0, stream, x, ws, out);
}

// Round 6
// 934.964 us; speedup vs baseline: 1.7226x; 1.7226x over previous
//
#include <hip/hip_runtime.h>
#include <math.h>

// ---------------- workspace layout (float2 units) ----------------
// ws_bs : 24 gates x 384  sector-packed BS: for sector N (size s, row SR=even(s)),
//                         g[SECBASE[N] + o*SR + ti] = U[j_o][k_ti]
// ws_g1 : 16 gates x 64   one-mode GT[k*8+j] with rotation/Kerr diagonals folded
#define WS_G1_OFF   (24*384)

typedef float v2f __attribute__((ext_vector_type(2)));
typedef float v4f __attribute__((ext_vector_type(4)));

// complex MAC: acc += s*g  via 2x v_pk_fma_f32 (all-VGPR operands)
__device__ __forceinline__ void cmac(v2f& acc, v2f s, v2f g){
  asm("v_pk_fma_f32 %0, %1, %2, %0 op_sel_hi:[0,1,1]\n\t"
      "v_pk_fma_f32 %0, %1, %2, %0 op_sel:[1,1,0] op_sel_hi:[1,0,1] neg_lo:[1,0,0]"
      : "+v"(acc) : "v"(s), "v"(g));
}

// async global->LDS, 16 B per lane. Global addr is per-lane; LDS base must be
// wave-uniform (data lands at lds + lane*16).
__device__ __forceinline__ void gld16(const float2* g, float2* l){
  __builtin_amdgcn_global_load_lds(
      (const __attribute__((address_space(1))) unsigned int*)g,
      (__attribute__((address_space(3))) unsigned int*)l, 16, 0, 0);
}

// state LDS swizzle: phys = idx ^ ((idx>>6)&15)  (bijective, no padding, 32768 B)
__device__ __forceinline__ int SW(int idx){ return idx ^ ((idx>>6)&15); }

// ---------------- setup: 24 beamsplitter 64x64 expm ----------------
__global__ __launch_bounds__(256) void setup_bs(
    const float* __restrict__ th1, const float* __restrict__ ph1,
    const float* __restrict__ th2, const float* __restrict__ ph2,
    float2* __restrict__ ws)
{
  __shared__ float2 bufA[4096];
  __shared__ float2 bufB[4096];
  const int g = blockIdx.x;          // 0..23
  const int t = threadIdx.x;
  const int l = g/12, intf = (g%12)/6, pos = g%6;
  const float th = (intf ? th2 : th1)[l*6+pos];
  const float ph = (intf ? ph2 : ph1)[l*6+pos];
  float nrm = fabsf(th)*14.0f;                 // row-sum norm bound
  int sq = 0;
  if (nrm > 0.25f) sq = (int)ceilf(log2f(nrm*4.0f));
  const float tc  = th * ldexpf(1.0f, -sq);    // scaled theta
  const float cph = cosf(ph), sph = sinf(ph);

  float2* cur = bufA; float2* nxt = bufB;
  for (int e=0;e<16;e++){ int idx=t*16+e;
    cur[idx] = make_float2(((idx>>6)==(idx&63))?1.f:0.f, 0.f); }
  __syncthreads();
  // Horner Taylor: B = I + Hs*B/k, k=12..1   (Hs applied sparsely: 2 taps/row)
  for (int k=12;k>=1;k--){
    const float inv = 1.0f/(float)k;
    for (int e=0;e<16;e++){
      const int idx=t*16+e; const int row=idx>>6, c=idx&63;
      const int m1=row>>3, m2=row&7;
      float vx=0.f, vy=0.f;
      if (m1<7 && m2>=1){
        const float mag = tc*sqrtf((float)((m1+1)*m2));
        const float2 q = cur[((m1+1)*8+(m2-1))*64 + c];
        vx += mag*(cph*q.x - sph*q.y);
        vy += mag*(cph*q.y + sph*q.x);
      }
      if (m1>=1 && m2<7){
        const float mag = tc*sqrtf((float)(m1*(m2+1)));
        const float2 q = cur[((m1-1)*8+(m2+1))*64 + c];
        vx -= mag*(cph*q.x + sph*q.y);
        vy -= mag*(cph*q.y - sph*q.x);
      }
      vx *= inv; vy *= inv;
      if (row==c) vx += 1.0f;
      nxt[idx] = make_float2(vx,vy);
    }
    __syncthreads();
    float2* tmp=cur; cur=nxt; nxt=tmp;
  }
  // squarings
  for (int si=0; si<sq; si++){
    for (int e=0;e<16;e++){
      const int idx=t*16+e; const int row=idx>>6, c=idx&63;
      float vx=0.f, vy=0.f;
      for (int q=0;q<64;q++){
        const float2 a_ = cur[row*64+q];
        const float2 b_ = cur[q*64+c];
        vx += a_.x*b_.x - a_.y*b_.y;
        vy += a_.x*b_.y + a_.y*b_.x;
      }
      nxt[idx] = make_float2(vx,vy);
    }
    __syncthreads();
    float2* tmp=cur; cur=nxt; nxt=tmp;
  }
  // sector-packed write: enumerate (N, o, ti-with-row-pad) linearly over 384 slots
  for (int e=t; e<384; e+=256){
    int rem = e, N = 0, S_=0, SR_=0;
    for (; N<15; N++){
      S_  = 8 - ((N<7)?(7-N):(N-7));
      SR_ = (S_+1)&~1;
      if (rem < S_*SR_) break;
      rem -= S_*SR_;
    }
    float2 v = make_float2(0.f,0.f);
    if (N < 15){
      const int o = rem / SR_, ti = rem % SR_;
      if (ti < S_){
        const int T0 = (N>7)?(N-7):0;
        const int j = 7*(T0+o)+N, k = 7*(T0+ti)+N;
        v = cur[j*64 + k];
      }
    }
    ws[g*384 + e] = v;
  }
}

// ---------------- setup: 16 one-mode 8x8 expm, diagonals folded in ----------------
__global__ __launch_bounds__(128) void setup_small(
    const float* __restrict__ rr,  const float* __restrict__ phr,
    const float* __restrict__ aa,  const float* __restrict__ pha,
    const float* __restrict__ vph1,const float* __restrict__ vph2,
    const float* __restrict__ kap,
    float2* __restrict__ ws_g1)
{
  const int g = blockIdx.x, t = threadIdx.x;   // g: 0..15
  __shared__ float2 h8[64], bufA[64], bufB[64];
  const int isSq = (g < 8);
  const int gi = isSq ? g : (g-8);
  const int li = gi>>2, m = gi&3;
  const float p1 = isSq ? rr[li*4+m]  : aa[li*4+m];
  const float p2 = isSq ? phr[li*4+m] : pha[li*4+m];
  const float nrm = fabsf(p1)*6.0f;
  int sq = 0; if (nrm > 0.25f) sq = (int)ceilf(log2f(nrm*4.0f));
  const float sc = ldexpf(1.0f,-sq);
  const float cp = cosf(p2), sp = sinf(p2);
  if (t < 64){
    const int row=t>>3, c=t&7;
    float2 v = make_float2(0.f,0.f);
    if (isSq){
      if (c == row+2){ const float mg = 0.5f*p1*sqrtf((float)((row+1)*(row+2)));
                       v = make_float2( mg*cp, -mg*sp); }
      else if (c+2 == row){ const float mg = 0.5f*p1*sqrtf((float)((row-1)*row));
                       v = make_float2(-mg*cp, -mg*sp); }
    } else {
      if (c+1 == row){ const float mg = p1*sqrtf((float)row);
                       v = make_float2( mg*cp,  mg*sp); }
      else if (c == row+1){ const float mg = p1*sqrtf((float)(row+1));
                       v = make_float2(-mg*cp,  mg*sp); }
    }
    h8[t]   = make_float2(v.x*sc, v.y*sc);
    bufA[t] = make_float2((row==c)?1.f:0.f, 0.f);
  }
  __syncthreads();
  float2* cur=bufA; float2* nxt=bufB;
  for (int k=12;k>=1;k--){
    const float inv = 1.0f/(float)k;
    if (t<64){
      const int row=t>>3, c=t&7;
      float vx=0.f, vy=0.f;
      for (int q=0;q<8;q++){
        const float2 a_=h8[row*8+q], b_=cur[q*8+c];
        vx += a_.x*b_.x - a_.y*b_.y; vy += a_.x*b_.y + a_.y*b_.x;
      }
      vx*=inv; vy*=inv; if (row==c) vx += 1.f;
      nxt[t]=make_float2(vx,vy);
    }
    __syncthreads();
    float2* tmp=cur; cur=nxt; nxt=tmp;
  }
  for (int si=0; si<sq; si++){
    if (t<64){
      const int row=t>>3, c=t&7;
      float vx=0.f, vy=0.f;
      for (int q=0;q<8;q++){
        const float2 a_=cur[row*8+q], b_=cur[q*8+c];
        vx += a_.x*b_.x - a_.y*b_.y; vy += a_.x*b_.y + a_.y*b_.x;
      }
      nxt[t]=make_float2(vx,vy);
    }
    __syncthreads();
    float2* tmp=cur; cur=nxt; nxt=tmp;
  }
  if (t<64){
    const int kk=t>>3, j=t&7;
    const float2 v = cur[j*8+kk];          // G[j][kk]
    float ang;
    if (isSq) ang = vph1[li*4+m]*(float)kk;
    else      ang = vph2[li*4+m]*(float)kk + kap[li*4+m]*(float)(j*j);
    const float ca = cosf(ang), sa = sinf(ang);
    ws_g1[g*64 + t] = make_float2(v.x*ca - v.y*sa, v.x*sa + v.y*ca);  // GT[k][j]
  }
}

// ---------------- main kernel ----------------
// State LDS, XOR-swizzled (no padding): phys = idx ^ ((idx>>6)&15).
// Logical strides i0:512 i1:64 i2:8 i3:1.
// bs_gate: lane = spectator; each wave owns disjoint photon-number sectors.
// Gates: double-buffered LDS staging via global_load_lds; reads are lane-
// invariant ds_read_b128/b64 (hardware broadcast, conflict-free, 0 VALU).

template<int NN,int PM>
__device__ __forceinline__ void bs_sector(const float2* gsec,
                                          float2* __restrict__ Sm,
                                          int lane, int A1, int X1, int B2, int C2)
{
  constexpr int S_ = 8 - ((NN<7)?(7-NN):(NN-7));
  constexpr int T0 = (NN>7)?(NN-7):0;
  constexpr int SR = (S_+1)&~1;
  int ka[S_];
  v2f sv[S_];
#pragma unroll
  for (int i=0;i<S_;i++){
    const int k = 7*(T0+i)+NN;
    int addr;
    if constexpr (PM==0)      addr = (lane ^ (k&15)) + 512*(k>>3) + 64*(k&7);
    else if constexpr (PM==1) addr = (A1 + 64*(k>>3) + 8*(k&7)) ^ ((k>>3) ^ X1);
    else                      addr = B2 + ((8*(k>>3) + (k&7)) ^ C2);
    ka[i] = addr;
    sv[i] = *(const v2f*)&Sm[addr];
  }
#pragma unroll
  for (int o=0;o<S_;o++){
    v2f acc = (v2f){0.f,0.f};
    const float2* row = gsec + o*SR;
#pragma unroll
    for (int p=0;p+1<S_;p+=2){
      const v4f gp = *(const v4f*)&row[p];        // ds_read_b128 broadcast
      cmac(acc, sv[p],   (v2f){gp.x,gp.y});
      cmac(acc, sv[p+1], (v2f){gp.z,gp.w});
    }
    if constexpr (S_&1){
      const v2f g = *(const v2f*)&row[S_-1];      // ds_read_b64 broadcast
      cmac(acc, sv[S_-1], g);
    }
    *(v2f*)&Sm[ka[o]] = acc;
  }
}

template<int PM>
__device__ __forceinline__ void bs_gate(const float2* gb,
                                        float2* __restrict__ Sm,
                                        int lane, int A1, int X1, int B2, int C2,
                                        int wvu)
{
  // per-wave sector lists, cmac-balanced: 85 / 84 / 87 / 88
  if (wvu==0){
    bs_sector<7 ,PM>(gb+156, Sm, lane,A1,X1,B2,C2);
    bs_sector<3 ,PM>(gb+18,  Sm, lane,A1,X1,B2,C2);
    bs_sector<13,PM>(gb+370, Sm, lane,A1,X1,B2,C2);
    bs_sector<0 ,PM>(gb+0,   Sm, lane,A1,X1,B2,C2);
  } else if (wvu==1){
    bs_sector<6 ,PM>(gb+100, Sm, lane,A1,X1,B2,C2);
    bs_sector<4 ,PM>(gb+34,  Sm, lane,A1,X1,B2,C2);
    bs_sector<2 ,PM>(gb+6,   Sm, lane,A1,X1,B2,C2);
    bs_sector<14,PM>(gb+374, Sm, lane,A1,X1,B2,C2);
  } else if (wvu==2){
    bs_sector<8 ,PM>(gb+220, Sm, lane,A1,X1,B2,C2);
    bs_sector<10,PM>(gb+312, Sm, lane,A1,X1,B2,C2);
    bs_sector<12,PM>(gb+358, Sm, lane,A1,X1,B2,C2);
    bs_sector<1 ,PM>(gb+2,   Sm, lane,A1,X1,B2,C2);
  } else {
    bs_sector<5 ,PM>(gb+64,  Sm, lane,A1,X1,B2,C2);
    bs_sector<9 ,PM>(gb+276, Sm, lane,A1,X1,B2,C2);
    bs_sector<11,PM>(gb+342, Sm, lane,A1,X1,B2,C2);
  }
  __syncthreads();
}

// one-mode gate on mode M; swizzled per-tap addresses, gates via LDS broadcast.
template<int M>
__device__ __forceinline__ void one_mode(const float2* gb,
                                         float2* __restrict__ Sm, int t)
{
  int ad[2][8];
#pragma unroll
  for (int vv=0; vv<2; vv++){
    const int v = t + vv*256;
    if constexpr (M==0){
      const int i1=(v>>6)&7;
      const int P = 64*i1 + ((v&63) ^ i1);
      const int P8 = P ^ 8;
#pragma unroll
      for (int k=0;k<8;k++) ad[vv][k] = ((k&1)?P8:P) + 512*k;
    } else if constexpr (M==1){
      const int i0=(v>>6)&7;
      const int P = 512*i0 + ((v&63) ^ ((i0&1)<<3));
#pragma unroll
      for (int k=0;k<8;k++) ad[vv][k] = (P ^ (k&7)) + 64*k;
    } else if constexpr (M==2){
      const int i0=((v>>3)&1)|(((v>>7)&3)<<1);
      const int i1=(v>>4)&7, i3=v&7;
      const int P = 512*i0 + 64*i1 + (i3 ^ i1);
      const int X8 = (i0&1)<<3;
#pragma unroll
      for (int k=0;k<8;k++) ad[vv][k] = P + ((8*k) ^ X8);
    } else {
      const int i0=(v>>4)&7, i1=v&7;
      const int i2=((v>>3)&1)|(((v>>7)&3)<<1);
      const int P = 512*i0 + 64*i1 + ((8*i2) ^ ((i0&1)<<3));
#pragma unroll
      for (int k=0;k<8;k++) ad[vv][k] = P + (k ^ i1);
    }
  }
  v2f acc[2][8];
#pragma unroll
  for (int vv=0; vv<2; vv++)
#pragma unroll
    for (int j=0;j<8;j++) acc[vv][j] = (v2f){0.f,0.f};
#pragma unroll
  for (int k=0;k<8;k++){
    const v2f sA = *(const v2f*)&Sm[ad[0][k]];
    const v2f sB = *(const v2f*)&Sm[ad[1][k]];
#pragma unroll
    for (int jj=0;jj<4;jj++){
      const v4f gp = *(const v4f*)&gb[k*8+jj*2];  // ds_read_b128 broadcast
      const v2f glo = (v2f){gp.x,gp.y};
      const v2f ghi = (v2f){gp.z,gp.w};
      cmac(acc[0][2*jj],   sA, glo);
      cmac(acc[1][2*jj],   sB, glo);
      cmac(acc[0][2*jj+1], sA, ghi);
      cmac(acc[1][2*jj+1], sB, ghi);
    }
  }
#pragma unroll
  for (int vv=0; vv<2; vv++)
#pragma unroll
    for (int j=0;j<8;j++) *(v2f*)&Sm[ad[vv][j]] = acc[vv][j];
  __syncthreads();
}

__global__ __launch_bounds__(256,4) void qnn_main(
    const float* __restrict__ x, const float2* __restrict__ ws,
    float* __restrict__ out)
{
  __shared__ __align__(16) float2 S[4096];       // state: 32 KiB, XOR-swizzled
  __shared__ __align__(16) float2 Gbs[2][384];   // bs gate double buffer (2x3 KiB)
  __shared__ __align__(16) float2 Gom[256];      // segment's 4 one-mode gates
  const int b = blockIdx.x, t = threadIdx.x;
  const int lane = t & 63;
  const int wvu = __builtin_amdgcn_readfirstlane(t>>6);
  const int i2c = (lane>>3)&7, i3c = lane&7;
  const float2* ws_g1 = ws + WS_G1_OFF;

  // coherent amplitudes c_n = e^{-x^2/2} x^n / sqrt(n!)  -- per-wave, via shuffles
  float c0[8]; float c1a, c1b, c23;
  {
    const float x0=x[b*4+0], x1=x[b*4+1], x2=x[b*4+2], x3=x[b*4+3];
    const int m=(lane>>3)&3;
    const float xv = (m&2)?((m&1)?x3:x2):((m&1)?x1:x0);
    float val = expf(-0.5f*xv*xv);
    const int n = lane&7;
#pragma unroll
    for (int q=1;q<8;q++) if (q<=n) val *= xv*rsqrtf((float)q);
    c23 = __shfl(val,16+i2c,64)*__shfl(val,24+i3c,64);
    c1a = __shfl(val,8+wvu,64); c1b = __shfl(val,12+wvu,64);
#pragma unroll
    for (int h=0;h<8;h++) c0[h] = __shfl(val,h,64);
  }
#pragma unroll
  for (int e=0;e<16;e++){
    const int idx = e*256 + t;
    S[SW(idx)] = make_float2(c0[e>>1]*((e&1)?c1b:c1a)*c23, 0.f);
  }
  // prologue: stage bs gate 0 (waves 0..2, 1 KiB each)
  if (wvu < 3) gld16(ws + (wvu*64+lane)*2, &Gbs[0][wvu*128]);
  __syncthreads();   // drains vmcnt -> gate 0 staged, state initialized

  // per-lane spectator constants for the bs pair maps
  const int A1 = 512*(lane>>3) + (lane&7);           // PM1: spect (i0,i3)
  const int X1 = ((lane>>3)&1)<<3;
  const int B2 = 512*(lane>>3) + 64*(lane&7);        // PM2: spect (i0,i1)
  const int C2 = (lane&7) | (((lane>>3)&1)<<3);

#pragma unroll 1
  for (int seg=0; seg<4; seg++){                     // seg = l*2 + r
    const float2* omg = ws_g1 + ((seg&1)*8 + (seg>>1)*4)*64;
#pragma unroll 1
    for (int q=0; q<6; q++){                         // pair pattern (0,1),(2,3),(1,2) x2
      const int gq = seg*6 + q;
      // stage next bs gate (waves 0..2) and this segment's om gates (wave 3)
      if (gq+1 < 24 && wvu < 3)
        gld16(ws + (gq+1)*384 + (wvu*64+lane)*2, &Gbs[(gq+1)&1][wvu*128]);
      if (q < 2 && wvu == 3)
        gld16(omg + q*128 + lane*2, &Gom[q*128]);
      const float2* gbuf = Gbs[gq&1];
      const int pm = (q>=3)?(q-3):q;
      if (pm==0)      bs_gate<0>(gbuf, S, lane,A1,X1,B2,C2, wvu);
      else if (pm==1) bs_gate<2>(gbuf, S, lane,A1,X1,B2,C2, wvu);
      else            bs_gate<1>(gbuf, S, lane,A1,X1,B2,C2, wvu);
    }
    one_mode<0>(Gom,     S, t);
    one_mode<1>(Gom+64,  S, t);
    one_mode<2>(Gom+128, S, t);
    one_mode<3>(Gom+192, S, t);
  }

  // <X_i> = 2 Re sum conj(s[n_i]) sqrt(n_i+1) s[n_i+1]
  const float w1a = sqrtf((float)(wvu+1));
  const float w1b = sqrtf((float)(wvu+5));
  const float w2 = sqrtf((float)(i2c+1)), w3 = sqrtf((float)(i3c+1));
  float am0=0.f, am1=0.f, am2=0.f, am3=0.f;
#pragma unroll
  for (int e=0;e<16;e++){
    const int idx = e*256 + t;
    const float2 a = S[SW(idx)];
    if ((e>>1) < 7){
      const float2 bz = S[SW(idx+512)];
      am0 = fmaf(a.x*bz.x + a.y*bz.y, sqrtf((float)((e>>1)+1)), am0);
    }
    if (((e&1)==0) || (wvu<3)){          // i1 = wvu + 4*(e&1)
      const float2 bz = S[SW(idx+64)];
      am1 = fmaf(a.x*bz.x + a.y*bz.y, (e&1)?w1b:w1a, am1);
    }
    if (i2c < 7){
      const float2 bz = S[SW(idx+8)];
      am2 = fmaf(a.x*bz.x + a.y*bz.y, w2, am2);
    }
    if (i3c < 7){
      const float2 bz = S[SW(idx+1)];
      am3 = fmaf(a.x*bz.x + a.y*bz.y, w3, am3);
    }
  }
#pragma unroll
  for (int o=32;o;o>>=1){
    am0 += __shfl_down(am0,o,64);
    am1 += __shfl_down(am1,o,64);
    am2 += __shfl_down(am2,o,64);
    am3 += __shfl_down(am3,o,64);
  }
  __syncthreads();                       // all state reads done before red reuses S
  float* red = (float*)S;
  if ((t&63)==0){
    red[wvu*4+0]=am0; red[wvu*4+1]=am1; red[wvu*4+2]=am2; red[wvu*4+3]=am3;
  }
  __syncthreads();
  if (t<4) out[b*4+t] = 2.f*(red[t]+red[4+t]+red[8+t]+red[12+t]);
}

// ---------------- host ----------------
extern "C" void kernel_launch(void* const* d_in, const int* in_sizes, int n_in,
                              void* d_out, int out_size, void* d_ws, size_t ws_size,
                              hipStream_t stream)
{
  const float* x    = (const float*)d_in[0];
  const float* th1  = (const float*)d_in[1];
  const float* ph1  = (const float*)d_in[2];
  const float* vph1 = (const float*)d_in[3];
  const float* rr   = (const float*)d_in[4];
  const float* phr  = (const float*)d_in[5];
  const float* th2  = (const float*)d_in[6];
  const float* ph2  = (const float*)d_in[7];
  const float* vph2 = (const float*)d_in[8];
  const float* aa   = (const float*)d_in[9];
  const float* pha  = (const float*)d_in[10];
  const float* kap  = (const float*)d_in[11];
  float2* ws  = (float2*)d_ws;
  float*  out = (float*)d_out;
  const int B = in_sizes[0] / 4;

  hipLaunchKernelGGL(setup_bs, dim3(24), dim3(256), 0, stream, th1, ph1, th2, ph2, ws);
  hipLaunchKernelGGL(setup_small, dim3(16), dim3(128), 0, stream,
                     rr, phr, aa, pha, vph1, vph2, kap, ws + WS_G1_OFF);
  hipLaunchKernelGGL(qnn_main, dim3(B), dim3(256), 0, stream, x, ws, out);
}

// Round 7
// 635.773 us; speedup vs baseline: 2.5332x; 1.4706x over previous
//
#include <hip/hip_runtime.h>
#include <math.h>

// ---------------- workspace layout (float2 units) ----------------
// ws_bs : 24 gates x 384  sector-packed BS: for sector N (size s, row SR=even(s)),
//                         g[SECBASE[N] + o*SR + ti] = U[j_o][k_ti]
// ws_g1 : 16 gates x 64   one-mode GT[k*8+j] with rotation/Kerr diagonals folded
#define WS_G1_OFF   (24*384)

typedef float v2f __attribute__((ext_vector_type(2)));
typedef float v4f __attribute__((ext_vector_type(4)));

// complex MAC: acc += s*g  via 2x v_pk_fma_f32 (all-VGPR operands)
__device__ __forceinline__ void cmac(v2f& acc, v2f s, v2f g){
  asm("v_pk_fma_f32 %0, %1, %2, %0 op_sel_hi:[0,1,1]\n\t"
      "v_pk_fma_f32 %0, %1, %2, %0 op_sel:[1,1,0] op_sel_hi:[1,0,1] neg_lo:[1,0,0]"
      : "+v"(acc) : "v"(s), "v"(g));
}

// state LDS swizzle: phys = idx ^ ((idx>>6)&15)  (bijective, no padding, 32768 B)
__device__ __forceinline__ int SW(int idx){ return idx ^ ((idx>>6)&15); }

// ---------------- setup: 24 beamsplitter 64x64 expm ----------------
// Element map idx = e*256+t: per-wave-uniform row (broadcast A reads),
// distinct columns across lanes (conflict-free B reads).
__global__ __launch_bounds__(256) void setup_bs(
    const float* __restrict__ th1, const float* __restrict__ ph1,
    const float* __restrict__ th2, const float* __restrict__ ph2,
    float2* __restrict__ ws)
{
  __shared__ float2 bufA[4096];
  __shared__ float2 bufB[4096];
  const int g = blockIdx.x;          // 0..23
  const int t = threadIdx.x;
  const int l = g/12, intf = (g%12)/6, pos = g%6;
  const float th = (intf ? th2 : th1)[l*6+pos];
  const float ph = (intf ? ph2 : ph1)[l*6+pos];
  float nrm = fabsf(th)*14.0f;                 // row-sum norm bound
  int sq = 0;
  if (nrm > 2.0f) sq = (int)ceilf(log2f(nrm*0.5f));   // Taylor-12 good to ||H||<=2
  const float tc  = th * ldexpf(1.0f, -sq);    // scaled theta
  const float cph = cosf(ph), sph = sinf(ph);

  float2* cur = bufA; float2* nxt = bufB;
  for (int e=0;e<16;e++){ int idx=e*256+t;
    cur[idx] = make_float2(((idx>>6)==(idx&63))?1.f:0.f, 0.f); }
  __syncthreads();
  // Horner Taylor: B = I + Hs*B/k, k=12..1   (Hs applied sparsely: 2 taps/row)
  for (int k=12;k>=1;k--){
    const float inv = 1.0f/(float)k;
    for (int e=0;e<16;e++){
      const int idx=e*256+t; const int row=idx>>6, c=idx&63;
      const int m1=row>>3, m2=row&7;
      float vx=0.f, vy=0.f;
      if (m1<7 && m2>=1){
        const float mag = tc*sqrtf((float)((m1+1)*m2));
        const float2 q = cur[((m1+1)*8+(m2-1))*64 + c];
        vx += mag*(cph*q.x - sph*q.y);
        vy += mag*(cph*q.y + sph*q.x);
      }
      if (m1>=1 && m2<7){
        const float mag = tc*sqrtf((float)(m1*(m2+1)));
        const float2 q = cur[((m1-1)*8+(m2+1))*64 + c];
        vx -= mag*(cph*q.x + sph*q.y);
        vy -= mag*(cph*q.y - sph*q.x);
      }
      vx *= inv; vy *= inv;
      if (row==c) vx += 1.0f;
      nxt[idx] = make_float2(vx,vy);
    }
    __syncthreads();
    float2* tmp=cur; cur=nxt; nxt=tmp;
  }
  // squarings: pk_fma pairs, broadcast A row, conflict-free B column
  for (int si=0; si<sq; si++){
    for (int e=0;e<16;e++){
      const int idx=e*256+t; const int row=idx>>6, c=idx&63;
      const float2* Arow = cur + row*64;
      v2f acc = (v2f){0.f,0.f};
      for (int q=0;q<64;q+=2){
        const v4f ap = *(const v4f*)&Arow[q];
        const v2f b0 = *(const v2f*)&cur[q*64+c];
        const v2f b1 = *(const v2f*)&cur[(q+1)*64+c];
        cmac(acc, b0, (v2f){ap.x,ap.y});
        cmac(acc, b1, (v2f){ap.z,ap.w});
      }
      nxt[idx] = make_float2(acc.x, acc.y);
    }
    __syncthreads();
    float2* tmp=cur; cur=nxt; nxt=tmp;
  }
  // sector-packed write: enumerate (N, o, ti-with-row-pad) linearly over 384 slots
  for (int e=t; e<384; e+=256){
    int rem = e, N = 0, S_=0, SR_=0;
    for (; N<15; N++){
      S_  = 8 - ((N<7)?(7-N):(N-7));
      SR_ = (S_+1)&~1;
      if (rem < S_*SR_) break;
      rem -= S_*SR_;
    }
    float2 v = make_float2(0.f,0.f);
    if (N < 15){
      const int o = rem / SR_, ti = rem % SR_;
      if (ti < S_){
        const int T0 = (N>7)?(N-7):0;
        const int j = 7*(T0+o)+N, k = 7*(T0+ti)+N;
        v = cur[j*64 + k];
      }
    }
    ws[g*384 + e] = v;
  }
}

// ---------------- setup: 16 one-mode 8x8 expm, diagonals folded in ----------------
__global__ __launch_bounds__(128) void setup_small(
    const float* __restrict__ rr,  const float* __restrict__ phr,
    const float* __restrict__ aa,  const float* __restrict__ pha,
    const float* __restrict__ vph1,const float* __restrict__ vph2,
    const float* __restrict__ kap,
    float2* __restrict__ ws_g1)
{
  const int g = blockIdx.x, t = threadIdx.x;   // g: 0..15
  __shared__ float2 h8[64], bufA[64], bufB[64];
  const int isSq = (g < 8);
  const int gi = isSq ? g : (g-8);
  const int li = gi>>2, m = gi&3;
  const float p1 = isSq ? rr[li*4+m]  : aa[li*4+m];
  const float p2 = isSq ? phr[li*4+m] : pha[li*4+m];
  const float nrm = fabsf(p1)*6.0f;
  int sq = 0; if (nrm > 2.0f) sq = (int)ceilf(log2f(nrm*0.5f));
  const float sc = ldexpf(1.0f,-sq);
  const float cp = cosf(p2), sp = sinf(p2);
  if (t < 64){
    const int row=t>>3, c=t&7;
    float2 v = make_float2(0.f,0.f);
    if (isSq){
      if (c == row+2){ const float mg = 0.5f*p1*sqrtf((float)((row+1)*(row+2)));
                       v = make_float2( mg*cp, -mg*sp); }
      else if (c+2 == row){ const float mg = 0.5f*p1*sqrtf((float)((row-1)*row));
                       v = make_float2(-mg*cp, -mg*sp); }
    } else {
      if (c+1 == row){ const float mg = p1*sqrtf((float)row);
                       v = make_float2( mg*cp,  mg*sp); }
      else if (c == row+1){ const float mg = p1*sqrtf((float)(row+1));
                       v = make_float2(-mg*cp,  mg*sp); }
    }
    h8[t]   = make_float2(v.x*sc, v.y*sc);
    bufA[t] = make_float2((row==c)?1.f:0.f, 0.f);
  }
  __syncthreads();
  float2* cur=bufA; float2* nxt=bufB;
  for (int k=12;k>=1;k--){
    const float inv = 1.0f/(float)k;
    if (t<64){
      const int row=t>>3, c=t&7;
      float vx=0.f, vy=0.f;
      for (int q=0;q<8;q++){
        const float2 a_=h8[row*8+q], b_=cur[q*8+c];
        vx += a_.x*b_.x - a_.y*b_.y; vy += a_.x*b_.y + a_.y*b_.x;
      }
      vx*=inv; vy*=inv; if (row==c) vx += 1.f;
      nxt[t]=make_float2(vx,vy);
    }
    __syncthreads();
    float2* tmp=cur; cur=nxt; nxt=tmp;
  }
  for (int si=0; si<sq; si++){
    if (t<64){
      const int row=t>>3, c=t&7;
      float vx=0.f, vy=0.f;
      for (int q=0;q<8;q++){
        const float2 a_=cur[row*8+q], b_=cur[q*8+c];
        vx += a_.x*b_.x - a_.y*b_.y; vy += a_.x*b_.y + a_.y*b_.x;
      }
      nxt[t]=make_float2(vx,vy);
    }
    __syncthreads();
    float2* tmp=cur; cur=nxt; nxt=tmp;
  }
  if (t<64){
    const int kk=t>>3, j=t&7;
    const float2 v = cur[j*8+kk];          // G[j][kk]
    float ang;
    if (isSq) ang = vph1[li*4+m]*(float)kk;
    else      ang = vph2[li*4+m]*(float)kk + kap[li*4+m]*(float)(j*j);
    const float ca = cosf(ang), sa = sinf(ang);
    ws_g1[g*64 + t] = make_float2(v.x*ca - v.y*sa, v.x*sa + v.y*ca);  // GT[k][j]
  }
}

// ---------------- main kernel ----------------
// State LDS, XOR-swizzled (no padding): phys = idx ^ ((idx>>6)&15).
// Logical strides i0:512 i1:64 i2:8 i3:1.
// bs_gate: lane = spectator; each wave owns disjoint photon-number sectors.
// Gate operands: LDS broadcast reads (ds_read_b128, 0 VALU); gate tables staged
// global->VGPR->ds_write (L2-cached VMEM, unlike global_load_lds which re-fetched
// 352 MB in R6), pipelined 2 phases ahead so L2 latency hides under compute.

template<int NN,int PM>
__device__ __forceinline__ void bs_sector(const float2* gsec,
                                          float2* __restrict__ Sm,
                                          int lane, int A1, int X1, int B2, int C2)
{
  constexpr int S_ = 8 - ((NN<7)?(7-NN):(NN-7));
  constexpr int T0 = (NN>7)?(NN-7):0;
  constexpr int SR = (S_+1)&~1;
  int ka[S_];
  v2f sv[S_];
#pragma unroll
  for (int i=0;i<S_;i++){
    const int k = 7*(T0+i)+NN;
    int addr;
    if constexpr (PM==0)      addr = (lane ^ (k&15)) + 512*(k>>3) + 64*(k&7);
    else if constexpr (PM==1) addr = (A1 + 64*(k>>3) + 8*(k&7)) ^ ((k>>3) ^ X1);
    else                      addr = B2 + ((8*(k>>3) + (k&7)) ^ C2);
    ka[i] = addr;
    sv[i] = *(const v2f*)&Sm[addr];
  }
#pragma unroll
  for (int o=0;o<S_;o++){
    v2f acc = (v2f){0.f,0.f};
    const float2* row = gsec + o*SR;
#pragma unroll
    for (int p=0;p+1<S_;p+=2){
      const v4f gp = *(const v4f*)&row[p];        // ds_read_b128 broadcast
      cmac(acc, sv[p],   (v2f){gp.x,gp.y});
      cmac(acc, sv[p+1], (v2f){gp.z,gp.w});
    }
    if constexpr (S_&1){
      const v2f g = *(const v2f*)&row[S_-1];      // ds_read_b64 broadcast
      cmac(acc, sv[S_-1], g);
    }
    *(v2f*)&Sm[ka[o]] = acc;
  }
}

template<int PM>
__device__ __forceinline__ void bs_gate(const float2* gb,
                                        float2* __restrict__ Sm,
                                        int lane, int A1, int X1, int B2, int C2,
                                        int wvu)
{
  // per-wave sector lists, cmac-balanced: 85 / 84 / 87 / 88
  if (wvu==0){
    bs_sector<7 ,PM>(gb+156, Sm, lane,A1,X1,B2,C2);
    bs_sector<3 ,PM>(gb+18,  Sm, lane,A1,X1,B2,C2);
    bs_sector<13,PM>(gb+370, Sm, lane,A1,X1,B2,C2);
    bs_sector<0 ,PM>(gb+0,   Sm, lane,A1,X1,B2,C2);
  } else if (wvu==1){
    bs_sector<6 ,PM>(gb+100, Sm, lane,A1,X1,B2,C2);
    bs_sector<4 ,PM>(gb+34,  Sm, lane,A1,X1,B2,C2);
    bs_sector<2 ,PM>(gb+6,   Sm, lane,A1,X1,B2,C2);
    bs_sector<14,PM>(gb+374, Sm, lane,A1,X1,B2,C2);
  } else if (wvu==2){
    bs_sector<8 ,PM>(gb+220, Sm, lane,A1,X1,B2,C2);
    bs_sector<10,PM>(gb+312, Sm, lane,A1,X1,B2,C2);
    bs_sector<12,PM>(gb+358, Sm, lane,A1,X1,B2,C2);
    bs_sector<1 ,PM>(gb+2,   Sm, lane,A1,X1,B2,C2);
  } else {
    bs_sector<5 ,PM>(gb+64,  Sm, lane,A1,X1,B2,C2);
    bs_sector<9 ,PM>(gb+276, Sm, lane,A1,X1,B2,C2);
    bs_sector<11,PM>(gb+342, Sm, lane,A1,X1,B2,C2);
  }
  __syncthreads();
}

// one-mode gate on mode M; swizzled per-tap addresses, gates via LDS broadcast.
template<int M>
__device__ __forceinline__ void one_mode(const float2* gb,
                                         float2* __restrict__ Sm, int t)
{
  int ad[2][8];
#pragma unroll
  for (int vv=0; vv<2; vv++){
    const int v = t + vv*256;
    if constexpr (M==0){
      const int i1=(v>>6)&7;
      const int P = 64*i1 + ((v&63) ^ i1);
      const int P8 = P ^ 8;
#pragma unroll
      for (int k=0;k<8;k++) ad[vv][k] = ((k&1)?P8:P) + 512*k;
    } else if constexpr (M==1){
      const int i0=(v>>6)&7;
      const int P = 512*i0 + ((v&63) ^ ((i0&1)<<3));
#pragma unroll
      for (int k=0;k<8;k++) ad[vv][k] = (P ^ (k&7)) + 64*k;
    } else if constexpr (M==2){
      const int i0=((v>>3)&1)|(((v>>7)&3)<<1);
      const int i1=(v>>4)&7, i3=v&7;
      const int P = 512*i0 + 64*i1 + (i3 ^ i1);
      const int X8 = (i0&1)<<3;
#pragma unroll
      for (int k=0;k<8;k++) ad[vv][k] = P + ((8*k) ^ X8);
    } else {
      const int i0=(v>>4)&7, i1=v&7;
      const int i2=((v>>3)&1)|(((v>>7)&3)<<1);
      const int P = 512*i0 + 64*i1 + ((8*i2) ^ ((i0&1)<<3));
#pragma unroll
      for (int k=0;k<8;k++) ad[vv][k] = P + (k ^ i1);
    }
  }
  v2f acc[2][8];
#pragma unroll
  for (int vv=0; vv<2; vv++)
#pragma unroll
    for (int j=0;j<8;j++) acc[vv][j] = (v2f){0.f,0.f};
#pragma unroll
  for (int k=0;k<8;k++){
    const v2f sA = *(const v2f*)&Sm[ad[0][k]];
    const v2f sB = *(const v2f*)&Sm[ad[1][k]];
#pragma unroll
    for (int jj=0;jj<4;jj++){
      const v4f gp = *(const v4f*)&gb[k*8+jj*2];  // ds_read_b128 broadcast
      const v2f glo = (v2f){gp.x,gp.y};
      const v2f ghi = (v2f){gp.z,gp.w};
      cmac(acc[0][2*jj],   sA, glo);
      cmac(acc[1][2*jj],   sB, glo);
      cmac(acc[0][2*jj+1], sA, ghi);
      cmac(acc[1][2*jj+1], sB, ghi);
    }
  }
#pragma unroll
  for (int vv=0; vv<2; vv++)
#pragma unroll
    for (int j=0;j<8;j++) *(v2f*)&Sm[ad[vv][j]] = acc[vv][j];
  __syncthreads();
}

__global__ __launch_bounds__(256,4) void qnn_main(
    const float* __restrict__ x, const float2* __restrict__ ws,
    float* __restrict__ out)
{
  __shared__ __align__(16) float2 S[4096];       // state: 32 KiB, XOR-swizzled
  __shared__ __align__(16) float2 Gbs[2][384];   // bs gate double buffer (2x3 KiB)
  __shared__ __align__(16) float2 Gom[256];      // segment's 4 one-mode gates
  const int b = blockIdx.x, t = threadIdx.x;
  const int lane = t & 63;
  const int wvu = __builtin_amdgcn_readfirstlane(t>>6);
  const int i2c = (lane>>3)&7, i3c = lane&7;
  const float2* ws_g1 = ws + WS_G1_OFF;
  const v4f* ws4 = (const v4f*)ws;               // 192 v4f per bs gate

  // coherent amplitudes c_n = e^{-x^2/2} x^n / sqrt(n!)  -- per-wave, via shuffles
  float c0[8]; float c1a, c1b, c23;
  {
    const float x0=x[b*4+0], x1=x[b*4+1], x2=x[b*4+2], x3=x[b*4+3];
    const int m=(lane>>3)&3;
    const float xv = (m&2)?((m&1)?x3:x2):((m&1)?x1:x0);
    float val = expf(-0.5f*xv*xv);
    const int n = lane&7;
#pragma unroll
    for (int q=1;q<8;q++) if (q<=n) val *= xv*rsqrtf((float)q);
    c23 = __shfl(val,16+i2c,64)*__shfl(val,24+i3c,64);
    c1a = __shfl(val,8+wvu,64); c1b = __shfl(val,12+wvu,64);
#pragma unroll
    for (int h=0;h<8;h++) c0[h] = __shfl(val,h,64);
  }
#pragma unroll
  for (int e=0;e<16;e++){
    const int idx = e*256 + t;
    S[SW(idx)] = make_float2(c0[e>>1]*((e&1)?c1b:c1a)*c23, 0.f);
  }
  // prologue: stage gates 0 and 1 directly (one-time vmcnt waits)
  v4f rS0, rS1, rOm;
  if (t < 192){
    const v4f a = ws4[t];            // gate 0
    const v4f bb = ws4[192 + t];     // gate 1
    *(v4f*)&Gbs[0][t*2] = a;
    *(v4f*)&Gbs[1][t*2] = bb;
  }
  __syncthreads();   // gates 0,1 staged; state initialized

  // per-lane spectator constants for the bs pair maps
  const int A1 = 512*(lane>>3) + (lane&7);           // PM1: spect (i0,i3)
  const int X1 = ((lane>>3)&1)<<3;
  const int B2 = 512*(lane>>3) + 64*(lane&7);        // PM2: spect (i0,i1)
  const int C2 = (lane&7) | (((lane>>3)&1)<<3);

#pragma unroll 1
  for (int seg=0; seg<4; seg++){                     // seg = l*2 + r
    const v4f* omg4 = (const v4f*)(ws_g1 + ((seg&1)*8 + (seg>>1)*4)*64);
#pragma unroll 1
    for (int q=0; q<6; q++){                         // pair pattern (0,1),(2,3),(1,2) x2
      const int gq = seg*6 + q;
      // --- staging pipeline: gate g lives in rS[g&1]; written one phase later
      if (t < 192){
        if (gq & 1){
          if (gq+1 < 24) *(v4f*)&Gbs[0][t*2] = rS0;      // gate gq+1 (even)
          if (gq+2 < 24) rS1 = ws4[(gq+2)*192 + t];      // load gate gq+2 (odd)
        } else {
          if (gq >= 1 && gq+1 < 24) *(v4f*)&Gbs[1][t*2] = rS1;  // gate gq+1 (odd)
          if (gq+2 < 24) rS0 = ws4[(gq+2)*192 + t];      // load gate gq+2 (even)
        }
      }
      if (t < 128){
        if (q == 4) *(v4f*)&Gom[t*2] = rOm;              // this segment's om gates
        if (q == 3) rOm = omg4[t];
      }
      // --- compute (ends with __syncthreads -> staged writes become visible)
      const float2* gbuf = Gbs[gq&1];
      const int pm = (q>=3)?(q-3):q;
      if (pm==0)      bs_gate<0>(gbuf, S, lane,A1,X1,B2,C2, wvu);
      else if (pm==1) bs_gate<2>(gbuf, S, lane,A1,X1,B2,C2, wvu);
      else            bs_gate<1>(gbuf, S, lane,A1,X1,B2,C2, wvu);
    }
    one_mode<0>(Gom,     S, t);
    one_mode<1>(Gom+64,  S, t);
    one_mode<2>(Gom+128, S, t);
    one_mode<3>(Gom+192, S, t);
  }

  // <X_i> = 2 Re sum conj(s[n_i]) sqrt(n_i+1) s[n_i+1]
  const float w1a = sqrtf((float)(wvu+1));
  const float w1b = sqrtf((float)(wvu+5));
  const float w2 = sqrtf((float)(i2c+1)), w3 = sqrtf((float)(i3c+1));
  float am0=0.f, am1=0.f, am2=0.f, am3=0.f;
#pragma unroll
  for (int e=0;e<16;e++){
    const int idx = e*256 + t;
    const float2 a = S[SW(idx)];
    if ((e>>1) < 7){
      const float2 bz = S[SW(idx+512)];
      am0 = fmaf(a.x*bz.x + a.y*bz.y, sqrtf((float)((e>>1)+1)), am0);
    }
    if (((e&1)==0) || (wvu<3)){          // i1 = wvu + 4*(e&1)
      const float2 bz = S[SW(idx+64)];
      am1 = fmaf(a.x*bz.x + a.y*bz.y, (e&1)?w1b:w1a, am1);
    }
    if (i2c < 7){
      const float2 bz = S[SW(idx+8)];
      am2 = fmaf(a.x*bz.x + a.y*bz.y, w2, am2);
    }
    if (i3c < 7){
      const float2 bz = S[SW(idx+1)];
      am3 = fmaf(a.x*bz.x + a.y*bz.y, w3, am3);
    }
  }
#pragma unroll
  for (int o=32;o;o>>=1){
    am0 += __shfl_down(am0,o,64);
    am1 += __shfl_down(am1,o,64);
    am2 += __shfl_down(am2,o,64);
    am3 += __shfl_down(am3,o,64);
  }
  __syncthreads();                       // all state reads done before red reuses S
  float* red = (float*)S;
  if ((t&63)==0){
    red[wvu*4+0]=am0; red[wvu*4+1]=am1; red[wvu*4+2]=am2; red[wvu*4+3]=am3;
  }
  __syncthreads();
  if (t<4) out[b*4+t] = 2.f*(red[t]+red[4+t]+red[8+t]+red[12+t]);
}

// ---------------- host ----------------
extern "C" void kernel_launch(void* const* d_in, const int* in_sizes, int n_in,
                              void* d_out, int out_size, void* d_ws, size_t ws_size,
                              hipStream_t stream)
{
  const float* x    = (const float*)d_in[0];
  const float* th1  = (const float*)d_in[1];
  const float* ph1  = (const float*)d_in[2];
  const float* vph1 = (const float*)d_in[3];
  const float* rr   = (const float*)d_in[4];
  const float* phr  = (const float*)d_in[5];
  const float* th2  = (const float*)d_in[6];
  const float* ph2  = (const float*)d_in[7];
  const float* vph2 = (const float*)d_in[8];
  const float* aa   = (const float*)d_in[9];
  const float* pha  = (const float*)d_in[10];
  const float* kap  = (const float*)d_in[11];
  float2* ws  = (float2*)d_ws;
  float*  out = (float*)d_out;
  const int B = in_sizes[0] / 4;

  hipLaunchKernelGGL(setup_bs, dim3(24), dim3(256), 0, stream, th1, ph1, th2, ph2, ws);
  hipLaunchKernelGGL(setup_small, dim3(16), dim3(128), 0, stream,
                     rr, phr, aa, pha, vph1, vph2, kap, ws + WS_G1_OFF);
  hipLaunchKernelGGL(qnn_main, dim3(B), dim3(256), 0, stream, x, ws, out);
}

// Round 8
// 627.272 us; speedup vs baseline: 2.5675x; 1.0136x over previous
//
#include <hip/hip_runtime.h>
#include <math.h>

// ---------------- workspace layout (float2 units) ----------------
// ws_bs : 24 gates x 384  sector-packed BS: for sector N (size s, row SR=even(s)),
//                         g[SECBASE[N] + o*SR + ti] = U[j_o][k_ti]
// ws_g1 : 16 gates x 64   one-mode GT[k*8+j] with rotation/Kerr diagonals folded
#define WS_G1_OFF   (24*384)

typedef float v2f __attribute__((ext_vector_type(2)));
typedef float v4f __attribute__((ext_vector_type(4)));

// complex MAC: acc += s*g  via 2x v_pk_fma_f32 (all-VGPR operands)
__device__ __forceinline__ void cmac(v2f& acc, v2f s, v2f g){
  asm("v_pk_fma_f32 %0, %1, %2, %0 op_sel_hi:[0,1,1]\n\t"
      "v_pk_fma_f32 %0, %1, %2, %0 op_sel:[1,1,0] op_sel_hi:[1,0,1] neg_lo:[1,0,0]"
      : "+v"(acc) : "v"(s), "v"(g));
}

// state LDS swizzle: phys = idx ^ ((idx>>6)&15)  (bijective, no padding, 32768 B)
__device__ __forceinline__ int SW(int idx){ return idx ^ ((idx>>6)&15); }

// ---------------- setup: 24 beamsplitter 64x64 expm ----------------
__global__ __launch_bounds__(256) void setup_bs(
    const float* __restrict__ th1, const float* __restrict__ ph1,
    const float* __restrict__ th2, const float* __restrict__ ph2,
    float2* __restrict__ ws)
{
  __shared__ float2 bufA[4096];
  __shared__ float2 bufB[4096];
  const int g = blockIdx.x;          // 0..23
  const int t = threadIdx.x;
  const int l = g/12, intf = (g%12)/6, pos = g%6;
  const float th = (intf ? th2 : th1)[l*6+pos];
  const float ph = (intf ? ph2 : ph1)[l*6+pos];
  float nrm = fabsf(th)*14.0f;                 // row-sum norm bound
  int sq = 0;
  if (nrm > 2.0f) sq = (int)ceilf(log2f(nrm*0.5f));   // Taylor-12 good to ||H||<=2
  const float tc  = th * ldexpf(1.0f, -sq);    // scaled theta
  const float cph = cosf(ph), sph = sinf(ph);

  float2* cur = bufA; float2* nxt = bufB;
  for (int e=0;e<16;e++){ int idx=e*256+t;
    cur[idx] = make_float2(((idx>>6)==(idx&63))?1.f:0.f, 0.f); }
  __syncthreads();
  // Horner Taylor: B = I + Hs*B/k, k=12..1   (Hs applied sparsely: 2 taps/row)
  for (int k=12;k>=1;k--){
    const float inv = 1.0f/(float)k;
    for (int e=0;e<16;e++){
      const int idx=e*256+t; const int row=idx>>6, c=idx&63;
      const int m1=row>>3, m2=row&7;
      float vx=0.f, vy=0.f;
      if (m1<7 && m2>=1){
        const float mag = tc*sqrtf((float)((m1+1)*m2));
        const float2 q = cur[((m1+1)*8+(m2-1))*64 + c];
        vx += mag*(cph*q.x - sph*q.y);
        vy += mag*(cph*q.y + sph*q.x);
      }
      if (m1>=1 && m2<7){
        const float mag = tc*sqrtf((float)(m1*(m2+1)));
        const float2 q = cur[((m1-1)*8+(m2+1))*64 + c];
        vx -= mag*(cph*q.x + sph*q.y);
        vy -= mag*(cph*q.y - sph*q.x);
      }
      vx *= inv; vy *= inv;
      if (row==c) vx += 1.0f;
      nxt[idx] = make_float2(vx,vy);
    }
    __syncthreads();
    float2* tmp=cur; cur=nxt; nxt=tmp;
  }
  // squarings: pk_fma pairs, broadcast A row, conflict-free B column
  for (int si=0; si<sq; si++){
    for (int e=0;e<16;e++){
      const int idx=e*256+t; const int row=idx>>6, c=idx&63;
      const float2* Arow = cur + row*64;
      v2f acc = (v2f){0.f,0.f};
      for (int q=0;q<64;q+=2){
        const v4f ap = *(const v4f*)&Arow[q];
        const v2f b0 = *(const v2f*)&cur[q*64+c];
        const v2f b1 = *(const v2f*)&cur[(q+1)*64+c];
        cmac(acc, b0, (v2f){ap.x,ap.y});
        cmac(acc, b1, (v2f){ap.z,ap.w});
      }
      nxt[idx] = make_float2(acc.x, acc.y);
    }
    __syncthreads();
    float2* tmp=cur; cur=nxt; nxt=tmp;
  }
  // sector-packed write: enumerate (N, o, ti-with-row-pad) linearly over 384 slots
  for (int e=t; e<384; e+=256){
    int rem = e, N = 0, S_=0, SR_=0;
    for (; N<15; N++){
      S_  = 8 - ((N<7)?(7-N):(N-7));
      SR_ = (S_+1)&~1;
      if (rem < S_*SR_) break;
      rem -= S_*SR_;
    }
    float2 v = make_float2(0.f,0.f);
    if (N < 15){
      const int o = rem / SR_, ti = rem % SR_;
      if (ti < S_){
        const int T0 = (N>7)?(N-7):0;
        const int j = 7*(T0+o)+N, k = 7*(T0+ti)+N;
        v = cur[j*64 + k];
      }
    }
    ws[g*384 + e] = v;
  }
}

// ---------------- setup: 16 one-mode 8x8 expm, diagonals folded in ----------------
__global__ __launch_bounds__(128) void setup_small(
    const float* __restrict__ rr,  const float* __restrict__ phr,
    const float* __restrict__ aa,  const float* __restrict__ pha,
    const float* __restrict__ vph1,const float* __restrict__ vph2,
    const float* __restrict__ kap,
    float2* __restrict__ ws_g1)
{
  const int g = blockIdx.x, t = threadIdx.x;   // g: 0..15
  __shared__ float2 h8[64], bufA[64], bufB[64];
  const int isSq = (g < 8);
  const int gi = isSq ? g : (g-8);
  const int li = gi>>2, m = gi&3;
  const float p1 = isSq ? rr[li*4+m]  : aa[li*4+m];
  const float p2 = isSq ? phr[li*4+m] : pha[li*4+m];
  const float nrm = fabsf(p1)*6.0f;
  int sq = 0; if (nrm > 2.0f) sq = (int)ceilf(log2f(nrm*0.5f));
  const float sc = ldexpf(1.0f,-sq);
  const float cp = cosf(p2), sp = sinf(p2);
  if (t < 64){
    const int row=t>>3, c=t&7;
    float2 v = make_float2(0.f,0.f);
    if (isSq){
      if (c == row+2){ const float mg = 0.5f*p1*sqrtf((float)((row+1)*(row+2)));
                       v = make_float2( mg*cp, -mg*sp); }
      else if (c+2 == row){ const float mg = 0.5f*p1*sqrtf((float)((row-1)*row));
                       v = make_float2(-mg*cp, -mg*sp); }
    } else {
      if (c+1 == row){ const float mg = p1*sqrtf((float)row);
                       v = make_float2( mg*cp,  mg*sp); }
      else if (c == row+1){ const float mg = p1*sqrtf((float)(row+1));
                       v = make_float2(-mg*cp,  mg*sp); }
    }
    h8[t]   = make_float2(v.x*sc, v.y*sc);
    bufA[t] = make_float2((row==c)?1.f:0.f, 0.f);
  }
  __syncthreads();
  float2* cur=bufA; float2* nxt=bufB;
  for (int k=12;k>=1;k--){
    const float inv = 1.0f/(float)k;
    if (t<64){
      const int row=t>>3, c=t&7;
      float vx=0.f, vy=0.f;
      for (int q=0;q<8;q++){
        const float2 a_=h8[row*8+q], b_=cur[q*8+c];
        vx += a_.x*b_.x - a_.y*b_.y; vy += a_.x*b_.y + a_.y*b_.x;
      }
      vx*=inv; vy*=inv; if (row==c) vx += 1.f;
      nxt[t]=make_float2(vx,vy);
    }
    __syncthreads();
    float2* tmp=cur; cur=nxt; nxt=tmp;
  }
  for (int si=0; si<sq; si++){
    if (t<64){
      const int row=t>>3, c=t&7;
      float vx=0.f, vy=0.f;
      for (int q=0;q<8;q++){
        const float2 a_=cur[row*8+q], b_=cur[q*8+c];
        vx += a_.x*b_.x - a_.y*b_.y; vy += a_.x*b_.y + a_.y*b_.x;
      }
      nxt[t]=make_float2(vx,vy);
    }
    __syncthreads();
    float2* tmp=cur; cur=nxt; nxt=tmp;
  }
  if (t<64){
    const int kk=t>>3, j=t&7;
    const float2 v = cur[j*8+kk];          // G[j][kk]
    float ang;
    if (isSq) ang = vph1[li*4+m]*(float)kk;
    else      ang = vph2[li*4+m]*(float)kk + kap[li*4+m]*(float)(j*j);
    const float ca = cosf(ang), sa = sinf(ang);
    ws_g1[g*64 + t] = make_float2(v.x*ca - v.y*sa, v.x*sa + v.y*ca);  // GT[k][j]
  }
}

// ---------------- main kernel ----------------
// State LDS, XOR-swizzled (no padding): phys = idx ^ ((idx>>6)&15).
// Logical strides i0:512 i1:64 i2:8 i3:1.
// bs_gate: lane = spectator; each wave owns disjoint photon-number sectors.
// Gate operands: LDS broadcast reads (ds_read_b128, 0 VALU). Gate tables staged
// global->VGPR->ds_write with STRICTLY intra-iteration register lifetime
// (R7's cross-iteration staging registers were spilled to scratch: 454 MB).

template<int NN,int PM>
__device__ __forceinline__ void bs_sector(const float2* gsec,
                                          float2* __restrict__ Sm,
                                          int lane, int A1, int X1, int B2, int C2)
{
  constexpr int S_ = 8 - ((NN<7)?(7-NN):(NN-7));
  constexpr int T0 = (NN>7)?(NN-7):0;
  constexpr int SR = (S_+1)&~1;
  int ka[S_];
  v2f sv[S_];
#pragma unroll
  for (int i=0;i<S_;i++){
    const int k = 7*(T0+i)+NN;
    int addr;
    if constexpr (PM==0)      addr = (lane ^ (k&15)) + 512*(k>>3) + 64*(k&7);
    else if constexpr (PM==1) addr = (A1 + 64*(k>>3) + 8*(k&7)) ^ ((k>>3) ^ X1);
    else                      addr = B2 + ((8*(k>>3) + (k&7)) ^ C2);
    ka[i] = addr;
    sv[i] = *(const v2f*)&Sm[addr];
  }
#pragma unroll
  for (int o=0;o<S_;o++){
    v2f acc = (v2f){0.f,0.f};
    const float2* row = gsec + o*SR;
#pragma unroll
    for (int p=0;p+1<S_;p+=2){
      const v4f gp = *(const v4f*)&row[p];        // ds_read_b128 broadcast
      cmac(acc, sv[p],   (v2f){gp.x,gp.y});
      cmac(acc, sv[p+1], (v2f){gp.z,gp.w});
    }
    if constexpr (S_&1){
      const v2f g = *(const v2f*)&row[S_-1];      // ds_read_b64 broadcast
      cmac(acc, sv[S_-1], g);
    }
    *(v2f*)&Sm[ka[o]] = acc;
  }
}

// NOTE: no trailing barrier -- caller stages the next gate, then barriers.
template<int PM>
__device__ __forceinline__ void bs_gate(const float2* gb,
                                        float2* __restrict__ Sm,
                                        int lane, int A1, int X1, int B2, int C2,
                                        int wvu)
{
  // per-wave sector lists, cmac-balanced: 85 / 84 / 87 / 88
  if (wvu==0){
    bs_sector<7 ,PM>(gb+156, Sm, lane,A1,X1,B2,C2);
    bs_sector<3 ,PM>(gb+18,  Sm, lane,A1,X1,B2,C2);
    bs_sector<13,PM>(gb+370, Sm, lane,A1,X1,B2,C2);
    bs_sector<0 ,PM>(gb+0,   Sm, lane,A1,X1,B2,C2);
  } else if (wvu==1){
    bs_sector<6 ,PM>(gb+100, Sm, lane,A1,X1,B2,C2);
    bs_sector<4 ,PM>(gb+34,  Sm, lane,A1,X1,B2,C2);
    bs_sector<2 ,PM>(gb+6,   Sm, lane,A1,X1,B2,C2);
    bs_sector<14,PM>(gb+374, Sm, lane,A1,X1,B2,C2);
  } else if (wvu==2){
    bs_sector<8 ,PM>(gb+220, Sm, lane,A1,X1,B2,C2);
    bs_sector<10,PM>(gb+312, Sm, lane,A1,X1,B2,C2);
    bs_sector<12,PM>(gb+358, Sm, lane,A1,X1,B2,C2);
    bs_sector<1 ,PM>(gb+2,   Sm, lane,A1,X1,B2,C2);
  } else {
    bs_sector<5 ,PM>(gb+64,  Sm, lane,A1,X1,B2,C2);
    bs_sector<9 ,PM>(gb+276, Sm, lane,A1,X1,B2,C2);
    bs_sector<11,PM>(gb+342, Sm, lane,A1,X1,B2,C2);
  }
}

// one-mode gate on mode M; swizzled per-tap addresses, gates via LDS broadcast.
template<int M>
__device__ __forceinline__ void one_mode(const float2* gb,
                                         float2* __restrict__ Sm, int t)
{
  int ad[2][8];
#pragma unroll
  for (int vv=0; vv<2; vv++){
    const int v = t + vv*256;
    if constexpr (M==0){
      const int i1=(v>>6)&7;
      const int P = 64*i1 + ((v&63) ^ i1);
      const int P8 = P ^ 8;
#pragma unroll
      for (int k=0;k<8;k++) ad[vv][k] = ((k&1)?P8:P) + 512*k;
    } else if constexpr (M==1){
      const int i0=(v>>6)&7;
      const int P = 512*i0 + ((v&63) ^ ((i0&1)<<3));
#pragma unroll
      for (int k=0;k<8;k++) ad[vv][k] = (P ^ (k&7)) + 64*k;
    } else if constexpr (M==2){
      const int i0=((v>>3)&1)|(((v>>7)&3)<<1);
      const int i1=(v>>4)&7, i3=v&7;
      const int P = 512*i0 + 64*i1 + (i3 ^ i1);
      const int X8 = (i0&1)<<3;
#pragma unroll
      for (int k=0;k<8;k++) ad[vv][k] = P + ((8*k) ^ X8);
    } else {
      const int i0=(v>>4)&7, i1=v&7;
      const int i2=((v>>3)&1)|(((v>>7)&3)<<1);
      const int P = 512*i0 + 64*i1 + ((8*i2) ^ ((i0&1)<<3));
#pragma unroll
      for (int k=0;k<8;k++) ad[vv][k] = P + (k ^ i1);
    }
  }
  v2f acc[2][8];
#pragma unroll
  for (int vv=0; vv<2; vv++)
#pragma unroll
    for (int j=0;j<8;j++) acc[vv][j] = (v2f){0.f,0.f};
#pragma unroll
  for (int k=0;k<8;k++){
    const v2f sA = *(const v2f*)&Sm[ad[0][k]];
    const v2f sB = *(const v2f*)&Sm[ad[1][k]];
#pragma unroll
    for (int jj=0;jj<4;jj++){
      const v4f gp = *(const v4f*)&gb[k*8+jj*2];  // ds_read_b128 broadcast
      const v2f glo = (v2f){gp.x,gp.y};
      const v2f ghi = (v2f){gp.z,gp.w};
      cmac(acc[0][2*jj],   sA, glo);
      cmac(acc[1][2*jj],   sB, glo);
      cmac(acc[0][2*jj+1], sA, ghi);
      cmac(acc[1][2*jj+1], sB, ghi);
    }
  }
  __syncthreads();
#pragma unroll
  for (int vv=0; vv<2; vv++)
#pragma unroll
    for (int j=0;j<8;j++) *(v2f*)&Sm[ad[vv][j]] = acc[vv][j];
  __syncthreads();
}

__global__ __launch_bounds__(256,4) void qnn_main(
    const float* __restrict__ x, const float2* __restrict__ ws,
    float* __restrict__ out)
{
  __shared__ __align__(16) float2 S[4096];       // state: 32 KiB, XOR-swizzled
  __shared__ __align__(16) float2 Gbs[2][384];   // bs gate double buffer (2x3 KiB)
  __shared__ __align__(16) float2 Gom[256];      // segment's 4 one-mode gates
  const int b = blockIdx.x, t = threadIdx.x;
  const int lane = t & 63;
  const int wvu = __builtin_amdgcn_readfirstlane(t>>6);
  const int i2c = (lane>>3)&7, i3c = lane&7;
  const float2* ws_g1 = ws + WS_G1_OFF;
  const v4f* ws4 = (const v4f*)ws;               // 192 v4f per bs gate

  // coherent amplitudes c_n = e^{-x^2/2} x^n / sqrt(n!)  -- per-wave, via shuffles
  float c0[8]; float c1a, c1b, c23;
  {
    const float x0=x[b*4+0], x1=x[b*4+1], x2=x[b*4+2], x3=x[b*4+3];
    const int m=(lane>>3)&3;
    const float xv = (m&2)?((m&1)?x3:x2):((m&1)?x1:x0);
    float val = expf(-0.5f*xv*xv);
    const int n = lane&7;
#pragma unroll
    for (int q=1;q<8;q++) if (q<=n) val *= xv*rsqrtf((float)q);
    c23 = __shfl(val,16+i2c,64)*__shfl(val,24+i3c,64);
    c1a = __shfl(val,8+wvu,64); c1b = __shfl(val,12+wvu,64);
#pragma unroll
    for (int h=0;h<8;h++) c0[h] = __shfl(val,h,64);
  }
#pragma unroll
  for (int e=0;e<16;e++){
    const int idx = e*256 + t;
    S[SW(idx)] = make_float2(c0[e>>1]*((e&1)?c1b:c1a)*c23, 0.f);
  }
  // prologue: stage gate 0 (intra-scope registers only)
  if (t < 192) *(v4f*)&Gbs[0][t*2] = ws4[t];
  __syncthreads();

  // per-lane spectator constants for the bs pair maps
  const int A1 = 512*(lane>>3) + (lane&7);           // PM1: spect (i0,i3)
  const int X1 = ((lane>>3)&1)<<3;
  const int B2 = 512*(lane>>3) + 64*(lane&7);        // PM2: spect (i0,i1)
  const int C2 = (lane&7) | (((lane>>3)&1)<<3);

#pragma unroll 1
  for (int seg=0; seg<4; seg++){                     // seg = l*2 + r
    const v4f* omg4 = (const v4f*)(ws_g1 + ((seg&1)*8 + (seg>>1)*4)*64);
#pragma unroll 1
    for (int q=0; q<6; q++){                         // pair pattern (0,1),(2,3),(1,2) x2
      const int gq = seg*6 + q;
      // issue staging loads (registers die within this iteration)
      const bool stB = (gq+1 < 24) && (t < 192);
      const bool stO = (q == 0) && (t < 128);
      v4f gB = (v4f){0.f,0.f,0.f,0.f}, gO = (v4f){0.f,0.f,0.f,0.f};
      if (stB) gB = ws4[(gq+1)*192 + t];
      if (stO) gO = omg4[t];
      // compute this phase (vmcnt wait for gB/gO overlaps all of it)
      const float2* gbuf = Gbs[gq&1];
      const int pm = (q>=3)?(q-3):q;
      if (pm==0)      bs_gate<0>(gbuf, S, lane,A1,X1,B2,C2, wvu);
      else if (pm==1) bs_gate<2>(gbuf, S, lane,A1,X1,B2,C2, wvu);
      else            bs_gate<1>(gbuf, S, lane,A1,X1,B2,C2, wvu);
      // write staged data to LDS (target buffer last read a full phase ago)
      if (stB) *(v4f*)&Gbs[(gq+1)&1][t*2] = gB;
      if (stO) *(v4f*)&Gom[t*2] = gO;
      __syncthreads();
    }
    one_mode<0>(Gom,     S, t);
    one_mode<1>(Gom+64,  S, t);
    one_mode<2>(Gom+128, S, t);
    one_mode<3>(Gom+192, S, t);
  }

  // <X_i> = 2 Re sum conj(s[n_i]) sqrt(n_i+1) s[n_i+1]
  const float w1a = sqrtf((float)(wvu+1));
  const float w1b = sqrtf((float)(wvu+5));
  const float w2 = sqrtf((float)(i2c+1)), w3 = sqrtf((float)(i3c+1));
  float am0=0.f, am1=0.f, am2=0.f, am3=0.f;
#pragma unroll
  for (int e=0;e<16;e++){
    const int idx = e*256 + t;
    const float2 a = S[SW(idx)];
    if ((e>>1) < 7){
      const float2 bz = S[SW(idx+512)];
      am0 = fmaf(a.x*bz.x + a.y*bz.y, sqrtf((float)((e>>1)+1)), am0);
    }
    if (((e&1)==0) || (wvu<3)){          // i1 = wvu + 4*(e&1)
      const float2 bz = S[SW(idx+64)];
      am1 = fmaf(a.x*bz.x + a.y*bz.y, (e&1)?w1b:w1a, am1);
    }
    if (i2c < 7){
      const float2 bz = S[SW(idx+8)];
      am2 = fmaf(a.x*bz.x + a.y*bz.y, w2, am2);
    }
    if (i3c < 7){
      const float2 bz = S[SW(idx+1)];
      am3 = fmaf(a.x*bz.x + a.y*bz.y, w3, am3);
    }
  }
#pragma unroll
  for (int o=32;o;o>>=1){
    am0 += __shfl_down(am0,o,64);
    am1 += __shfl_down(am1,o,64);
    am2 += __shfl_down(am2,o,64);
    am3 += __shfl_down(am3,o,64);
  }
  __syncthreads();                       // all state reads done before red reuses S
  float* red = (float*)S;
  if ((t&63)==0){
    red[wvu*4+0]=am0; red[wvu*4+1]=am1; red[wvu*4+2]=am2; red[wvu*4+3]=am3;
  }
  __syncthreads();
  if (t<4) out[b*4+t] = 2.f*(red[t]+red[4+t]+red[8+t]+red[12+t]);
}

// ---------------- host ----------------
extern "C" void kernel_launch(void* const* d_in, const int* in_sizes, int n_in,
                              void* d_out, int out_size, void* d_ws, size_t ws_size,
                              hipStream_t stream)
{
  const float* x    = (const float*)d_in[0];
  const float* th1  = (const float*)d_in[1];
  const float* ph1  = (const float*)d_in[2];
  const float* vph1 = (const float*)d_in[3];
  const float* rr   = (const float*)d_in[4];
  const float* phr  = (const float*)d_in[5];
  const float* th2  = (const float*)d_in[6];
  const float* ph2  = (const float*)d_in[7];
  const float* vph2 = (const float*)d_in[8];
  const float* aa   = (const float*)d_in[9];
  const float* pha  = (const float*)d_in[10];
  const float* kap  = (const float*)d_in[11];
  float2* ws  = (float2*)d_ws;
  float*  out = (float*)d_out;
  const int B = in_sizes[0] / 4;

  hipLaunchKernelGGL(setup_bs, dim3(24), dim3(256), 0, stream, th1, ph1, th2, ph2, ws);
  hipLaunchKernelGGL(setup_small, dim3(16), dim3(128), 0, stream,
                     rr, phr, aa, pha, vph1, vph2, kap, ws + WS_G1_OFF);
  hipLaunchKernelGGL(qnn_main, dim3(B), dim3(256), 0, stream, x, ws, out);
}

// Round 9
// 619.623 us; speedup vs baseline: 2.5992x; 1.0123x over previous
//
#include <hip/hip_runtime.h>
#include <math.h>

// ---------------- workspace layout (float2 units) ----------------
// ws_bs : 24 gates x 384  sector-packed BS: for sector N (size s, row SR=even(s)),
//                         g[SECBASE[N] + o*SR + ti] = U[j_o][k_ti]
// ws_g1 : 16 gates x 64   one-mode GT[k*8+j] with rotation/Kerr diagonals folded
#define WS_G1_OFF   (24*384)

typedef float v2f __attribute__((ext_vector_type(2)));
typedef float v4f __attribute__((ext_vector_type(4)));

// complex MAC: acc += s*g  via 2x v_pk_fma_f32 (all-VGPR operands)
__device__ __forceinline__ void cmac(v2f& acc, v2f s, v2f g){
  asm("v_pk_fma_f32 %0, %1, %2, %0 op_sel_hi:[0,1,1]\n\t"
      "v_pk_fma_f32 %0, %1, %2, %0 op_sel:[1,1,0] op_sel_hi:[1,0,1] neg_lo:[1,0,0]"
      : "+v"(acc) : "v"(s), "v"(g));
}

// state LDS swizzle: phys = idx ^ ((idx>>6)&15)  (bijective, no padding, 32768 B)
__device__ __forceinline__ int SW(int idx){ return idx ^ ((idx>>6)&15); }

// ---------------- setup: 24 beamsplitter 64x64 expm ----------------
__global__ __launch_bounds__(256) void setup_bs(
    const float* __restrict__ th1, const float* __restrict__ ph1,
    const float* __restrict__ th2, const float* __restrict__ ph2,
    float2* __restrict__ ws)
{
  __shared__ float2 bufA[4096];
  __shared__ float2 bufB[4096];
  const int g = blockIdx.x;          // 0..23
  const int t = threadIdx.x;
  const int l = g/12, intf = (g%12)/6, pos = g%6;
  const float th = (intf ? th2 : th1)[l*6+pos];
  const float ph = (intf ? ph2 : ph1)[l*6+pos];
  float nrm = fabsf(th)*14.0f;                 // row-sum norm bound
  int sq = 0;
  if (nrm > 2.0f) sq = (int)ceilf(log2f(nrm*0.5f));   // Taylor-12 good to ||H||<=2
  const float tc  = th * ldexpf(1.0f, -sq);    // scaled theta
  const float cph = cosf(ph), sph = sinf(ph);

  float2* cur = bufA; float2* nxt = bufB;
  for (int e=0;e<16;e++){ int idx=e*256+t;
    cur[idx] = make_float2(((idx>>6)==(idx&63))?1.f:0.f, 0.f); }
  __syncthreads();
  // Horner Taylor: B = I + Hs*B/k, k=12..1   (Hs applied sparsely: 2 taps/row)
  for (int k=12;k>=1;k--){
    const float inv = 1.0f/(float)k;
    for (int e=0;e<16;e++){
      const int idx=e*256+t; const int row=idx>>6, c=idx&63;
      const int m1=row>>3, m2=row&7;
      float vx=0.f, vy=0.f;
      if (m1<7 && m2>=1){
        const float mag = tc*sqrtf((float)((m1+1)*m2));
        const float2 q = cur[((m1+1)*8+(m2-1))*64 + c];
        vx += mag*(cph*q.x - sph*q.y);
        vy += mag*(cph*q.y + sph*q.x);
      }
      if (m1>=1 && m2<7){
        const float mag = tc*sqrtf((float)(m1*(m2+1)));
        const float2 q = cur[((m1-1)*8+(m2+1))*64 + c];
        vx -= mag*(cph*q.x + sph*q.y);
        vy -= mag*(cph*q.y - sph*q.x);
      }
      vx *= inv; vy *= inv;
      if (row==c) vx += 1.0f;
      nxt[idx] = make_float2(vx,vy);
    }
    __syncthreads();
    float2* tmp=cur; cur=nxt; nxt=tmp;
  }
  // squarings: pk_fma pairs, broadcast A row, conflict-free B column
  for (int si=0; si<sq; si++){
    for (int e=0;e<16;e++){
      const int idx=e*256+t; const int row=idx>>6, c=idx&63;
      const float2* Arow = cur + row*64;
      v2f acc = (v2f){0.f,0.f};
      for (int q=0;q<64;q+=2){
        const v4f ap = *(const v4f*)&Arow[q];
        const v2f b0 = *(const v2f*)&cur[q*64+c];
        const v2f b1 = *(const v2f*)&cur[(q+1)*64+c];
        cmac(acc, b0, (v2f){ap.x,ap.y});
        cmac(acc, b1, (v2f){ap.z,ap.w});
      }
      nxt[idx] = make_float2(acc.x, acc.y);
    }
    __syncthreads();
    float2* tmp=cur; cur=nxt; nxt=tmp;
  }
  // sector-packed write: enumerate (N, o, ti-with-row-pad) linearly over 384 slots
  for (int e=t; e<384; e+=256){
    int rem = e, N = 0, S_=0, SR_=0;
    for (; N<15; N++){
      S_  = 8 - ((N<7)?(7-N):(N-7));
      SR_ = (S_+1)&~1;
      if (rem < S_*SR_) break;
      rem -= S_*SR_;
    }
    float2 v = make_float2(0.f,0.f);
    if (N < 15){
      const int o = rem / SR_, ti = rem % SR_;
      if (ti < S_){
        const int T0 = (N>7)?(N-7):0;
        const int j = 7*(T0+o)+N, k = 7*(T0+ti)+N;
        v = cur[j*64 + k];
      }
    }
    ws[g*384 + e] = v;
  }
}

// ---------------- setup: 16 one-mode 8x8 expm, diagonals folded in ----------------
__global__ __launch_bounds__(128) void setup_small(
    const float* __restrict__ rr,  const float* __restrict__ phr,
    const float* __restrict__ aa,  const float* __restrict__ pha,
    const float* __restrict__ vph1,const float* __restrict__ vph2,
    const float* __restrict__ kap,
    float2* __restrict__ ws_g1)
{
  const int g = blockIdx.x, t = threadIdx.x;   // g: 0..15
  __shared__ float2 h8[64], bufA[64], bufB[64];
  const int isSq = (g < 8);
  const int gi = isSq ? g : (g-8);
  const int li = gi>>2, m = gi&3;
  const float p1 = isSq ? rr[li*4+m]  : aa[li*4+m];
  const float p2 = isSq ? phr[li*4+m] : pha[li*4+m];
  const float nrm = fabsf(p1)*6.0f;
  int sq = 0; if (nrm > 2.0f) sq = (int)ceilf(log2f(nrm*0.5f));
  const float sc = ldexpf(1.0f,-sq);
  const float cp = cosf(p2), sp = sinf(p2);
  if (t < 64){
    const int row=t>>3, c=t&7;
    float2 v = make_float2(0.f,0.f);
    if (isSq){
      if (c == row+2){ const float mg = 0.5f*p1*sqrtf((float)((row+1)*(row+2)));
                       v = make_float2( mg*cp, -mg*sp); }
      else if (c+2 == row){ const float mg = 0.5f*p1*sqrtf((float)((row-1)*row));
                       v = make_float2(-mg*cp, -mg*sp); }
    } else {
      if (c+1 == row){ const float mg = p1*sqrtf((float)row);
                       v = make_float2( mg*cp,  mg*sp); }
      else if (c == row+1){ const float mg = p1*sqrtf((float)(row+1));
                       v = make_float2(-mg*cp,  mg*sp); }
    }
    h8[t]   = make_float2(v.x*sc, v.y*sc);
    bufA[t] = make_float2((row==c)?1.f:0.f, 0.f);
  }
  __syncthreads();
  float2* cur=bufA; float2* nxt=bufB;
  for (int k=12;k>=1;k--){
    const float inv = 1.0f/(float)k;
    if (t<64){
      const int row=t>>3, c=t&7;
      float vx=0.f, vy=0.f;
      for (int q=0;q<8;q++){
        const float2 a_=h8[row*8+q], b_=cur[q*8+c];
        vx += a_.x*b_.x - a_.y*b_.y; vy += a_.x*b_.y + a_.y*b_.x;
      }
      vx*=inv; vy*=inv; if (row==c) vx += 1.f;
      nxt[t]=make_float2(vx,vy);
    }
    __syncthreads();
    float2* tmp=cur; cur=nxt; nxt=tmp;
  }
  for (int si=0; si<sq; si++){
    if (t<64){
      const int row=t>>3, c=t&7;
      float vx=0.f, vy=0.f;
      for (int q=0;q<8;q++){
        const float2 a_=cur[row*8+q], b_=cur[q*8+c];
        vx += a_.x*b_.x - a_.y*b_.y; vy += a_.x*b_.y + a_.y*b_.x;
      }
      nxt[t]=make_float2(vx,vy);
    }
    __syncthreads();
    float2* tmp=cur; cur=nxt; nxt=tmp;
  }
  if (t<64){
    const int kk=t>>3, j=t&7;
    const float2 v = cur[j*8+kk];          // G[j][kk]
    float ang;
    if (isSq) ang = vph1[li*4+m]*(float)kk;
    else      ang = vph2[li*4+m]*(float)kk + kap[li*4+m]*(float)(j*j);
    const float ca = cosf(ang), sa = sinf(ang);
    ws_g1[g*64 + t] = make_float2(v.x*ca - v.y*sa, v.x*sa + v.y*ca);  // GT[k][j]
  }
}

// ---------------- main kernel ----------------
// State LDS, XOR-swizzled (no padding): phys = idx ^ ((idx>>6)&15).
// Logical strides i0:512 i1:64 i2:8 i3:1.
// bs_gate: lane = spectator; each wave owns disjoint photon-number sectors.
// Gate operands: LDS broadcast reads (ds_read_b128, 0 VALU). Staging is
// load -> IMMEDIATE ds_write (3-instruction register lifetime -- R7/R8 kept
// the staged value live across the compute body and it spilled to scratch,
// 393-454 MB of scratch traffic). L2-hit stall at phase start is covered by
// the 16 resident waves/CU.

template<int NN,int PM>
__device__ __forceinline__ void bs_sector(const float2* gsec,
                                          float2* __restrict__ Sm,
                                          int lane, int A1, int X1, int B2, int C2)
{
  constexpr int S_ = 8 - ((NN<7)?(7-NN):(NN-7));
  constexpr int T0 = (NN>7)?(NN-7):0;
  constexpr int SR = (S_+1)&~1;
  int ka[S_];
  v2f sv[S_];
#pragma unroll
  for (int i=0;i<S_;i++){
    const int k = 7*(T0+i)+NN;
    int addr;
    if constexpr (PM==0)      addr = (lane ^ (k&15)) + 512*(k>>3) + 64*(k&7);
    else if constexpr (PM==1) addr = (A1 + 64*(k>>3) + 8*(k&7)) ^ ((k>>3) ^ X1);
    else                      addr = B2 + ((8*(k>>3) + (k&7)) ^ C2);
    ka[i] = addr;
    sv[i] = *(const v2f*)&Sm[addr];
  }
#pragma unroll
  for (int o=0;o<S_;o++){
    v2f acc = (v2f){0.f,0.f};
    const float2* row = gsec + o*SR;
#pragma unroll
    for (int p=0;p+1<S_;p+=2){
      const v4f gp = *(const v4f*)&row[p];        // ds_read_b128 broadcast
      cmac(acc, sv[p],   (v2f){gp.x,gp.y});
      cmac(acc, sv[p+1], (v2f){gp.z,gp.w});
    }
    if constexpr (S_&1){
      const v2f g = *(const v2f*)&row[S_-1];      // ds_read_b64 broadcast
      cmac(acc, sv[S_-1], g);
    }
    *(v2f*)&Sm[ka[o]] = acc;
  }
}

// NOTE: no trailing barrier -- caller barriers after the phase.
template<int PM>
__device__ __forceinline__ void bs_gate(const float2* gb,
                                        float2* __restrict__ Sm,
                                        int lane, int A1, int X1, int B2, int C2,
                                        int wvu)
{
  // per-wave sector lists, cmac-balanced: 85 / 84 / 87 / 88
  if (wvu==0){
    bs_sector<7 ,PM>(gb+156, Sm, lane,A1,X1,B2,C2);
    bs_sector<3 ,PM>(gb+18,  Sm, lane,A1,X1,B2,C2);
    bs_sector<13,PM>(gb+370, Sm, lane,A1,X1,B2,C2);
    bs_sector<0 ,PM>(gb+0,   Sm, lane,A1,X1,B2,C2);
  } else if (wvu==1){
    bs_sector<6 ,PM>(gb+100, Sm, lane,A1,X1,B2,C2);
    bs_sector<4 ,PM>(gb+34,  Sm, lane,A1,X1,B2,C2);
    bs_sector<2 ,PM>(gb+6,   Sm, lane,A1,X1,B2,C2);
    bs_sector<14,PM>(gb+374, Sm, lane,A1,X1,B2,C2);
  } else if (wvu==2){
    bs_sector<8 ,PM>(gb+220, Sm, lane,A1,X1,B2,C2);
    bs_sector<10,PM>(gb+312, Sm, lane,A1,X1,B2,C2);
    bs_sector<12,PM>(gb+358, Sm, lane,A1,X1,B2,C2);
    bs_sector<1 ,PM>(gb+2,   Sm, lane,A1,X1,B2,C2);
  } else {
    bs_sector<5 ,PM>(gb+64,  Sm, lane,A1,X1,B2,C2);
    bs_sector<9 ,PM>(gb+276, Sm, lane,A1,X1,B2,C2);
    bs_sector<11,PM>(gb+342, Sm, lane,A1,X1,B2,C2);
  }
}

// one-mode gate on mode M; swizzled per-tap addresses, gates via LDS broadcast.
template<int M>
__device__ __forceinline__ void one_mode(const float2* gb,
                                         float2* __restrict__ Sm, int t)
{
  int ad[2][8];
#pragma unroll
  for (int vv=0; vv<2; vv++){
    const int v = t + vv*256;
    if constexpr (M==0){
      const int i1=(v>>6)&7;
      const int P = 64*i1 + ((v&63) ^ i1);
      const int P8 = P ^ 8;
#pragma unroll
      for (int k=0;k<8;k++) ad[vv][k] = ((k&1)?P8:P) + 512*k;
    } else if constexpr (M==1){
      const int i0=(v>>6)&7;
      const int P = 512*i0 + ((v&63) ^ ((i0&1)<<3));
#pragma unroll
      for (int k=0;k<8;k++) ad[vv][k] = (P ^ (k&7)) + 64*k;
    } else if constexpr (M==2){
      const int i0=((v>>3)&1)|(((v>>7)&3)<<1);
      const int i1=(v>>4)&7, i3=v&7;
      const int P = 512*i0 + 64*i1 + (i3 ^ i1);
      const int X8 = (i0&1)<<3;
#pragma unroll
      for (int k=0;k<8;k++) ad[vv][k] = P + ((8*k) ^ X8);
    } else {
      const int i0=(v>>4)&7, i1=v&7;
      const int i2=((v>>3)&1)|(((v>>7)&3)<<1);
      const int P = 512*i0 + 64*i1 + ((8*i2) ^ ((i0&1)<<3));
#pragma unroll
      for (int k=0;k<8;k++) ad[vv][k] = P + (k ^ i1);
    }
  }
  v2f acc[2][8];
#pragma unroll
  for (int vv=0; vv<2; vv++)
#pragma unroll
    for (int j=0;j<8;j++) acc[vv][j] = (v2f){0.f,0.f};
#pragma unroll
  for (int k=0;k<8;k++){
    const v2f sA = *(const v2f*)&Sm[ad[0][k]];
    const v2f sB = *(const v2f*)&Sm[ad[1][k]];
#pragma unroll
    for (int jj=0;jj<4;jj++){
      const v4f gp = *(const v4f*)&gb[k*8+jj*2];  // ds_read_b128 broadcast
      const v2f glo = (v2f){gp.x,gp.y};
      const v2f ghi = (v2f){gp.z,gp.w};
      cmac(acc[0][2*jj],   sA, glo);
      cmac(acc[1][2*jj],   sB, glo);
      cmac(acc[0][2*jj+1], sA, ghi);
      cmac(acc[1][2*jj+1], sB, ghi);
    }
  }
  __syncthreads();
#pragma unroll
  for (int vv=0; vv<2; vv++)
#pragma unroll
    for (int j=0;j<8;j++) *(v2f*)&Sm[ad[vv][j]] = acc[vv][j];
  __syncthreads();
}

__global__ __launch_bounds__(256,4) void qnn_main(
    const float* __restrict__ x, const float2* __restrict__ ws,
    float* __restrict__ out)
{
  __shared__ __align__(16) float2 S[4096];       // state: 32 KiB, XOR-swizzled
  __shared__ __align__(16) float2 Gbs[2][384];   // bs gate double buffer (2x3 KiB)
  __shared__ __align__(16) float2 Gom[256];      // segment's 4 one-mode gates
  const int b = blockIdx.x, t = threadIdx.x;
  const int lane = t & 63;
  const int wvu = __builtin_amdgcn_readfirstlane(t>>6);
  const int i2c = (lane>>3)&7, i3c = lane&7;
  const float2* ws_g1 = ws + WS_G1_OFF;
  const v4f* ws4 = (const v4f*)ws;               // 192 v4f per bs gate

  // coherent amplitudes c_n = e^{-x^2/2} x^n / sqrt(n!)  -- per-wave, via shuffles
  float c0[8]; float c1a, c1b, c23;
  {
    const float x0=x[b*4+0], x1=x[b*4+1], x2=x[b*4+2], x3=x[b*4+3];
    const int m=(lane>>3)&3;
    const float xv = (m&2)?((m&1)?x3:x2):((m&1)?x1:x0);
    float val = expf(-0.5f*xv*xv);
    const int n = lane&7;
#pragma unroll
    for (int q=1;q<8;q++) if (q<=n) val *= xv*rsqrtf((float)q);
    c23 = __shfl(val,16+i2c,64)*__shfl(val,24+i3c,64);
    c1a = __shfl(val,8+wvu,64); c1b = __shfl(val,12+wvu,64);
#pragma unroll
    for (int h=0;h<8;h++) c0[h] = __shfl(val,h,64);
  }
#pragma unroll
  for (int e=0;e<16;e++){
    const int idx = e*256 + t;
    S[SW(idx)] = make_float2(c0[e>>1]*((e&1)?c1b:c1a)*c23, 0.f);
  }
  // prologue: stage gate 0
  if (t < 192) *(v4f*)&Gbs[0][t*2] = ws4[t];
  __syncthreads();

  // per-lane spectator constants for the bs pair maps
  const int A1 = 512*(lane>>3) + (lane&7);           // PM1: spect (i0,i3)
  const int X1 = ((lane>>3)&1)<<3;
  const int B2 = 512*(lane>>3) + 64*(lane&7);        // PM2: spect (i0,i1)
  const int C2 = (lane&7) | (((lane>>3)&1)<<3);

#pragma unroll 1
  for (int seg=0; seg<4; seg++){                     // seg = l*2 + r
    const v4f* omg4 = (const v4f*)(ws_g1 + ((seg&1)*8 + (seg>>1)*4)*64);
#pragma unroll 1
    for (int q=0; q<6; q++){                         // pair pattern (0,1),(2,3),(1,2) x2
      const int gq = seg*6 + q;
      // stage next gate: load -> immediate ds_write (no live-across-compute regs)
      if (gq+1 < 24 && t < 192)
        *(v4f*)&Gbs[(gq+1)&1][t*2] = ws4[(gq+1)*192 + t];
      if (q == 0 && t < 128)
        *(v4f*)&Gom[t*2] = omg4[t];
      // compute this phase
      const float2* gbuf = Gbs[gq&1];
      const int pm = (q>=3)?(q-3):q;
      if (pm==0)      bs_gate<0>(gbuf, S, lane,A1,X1,B2,C2, wvu);
      else if (pm==1) bs_gate<2>(gbuf, S, lane,A1,X1,B2,C2, wvu);
      else            bs_gate<1>(gbuf, S, lane,A1,X1,B2,C2, wvu);
      __syncthreads();
    }
    one_mode<0>(Gom,     S, t);
    one_mode<1>(Gom+64,  S, t);
    one_mode<2>(Gom+128, S, t);
    one_mode<3>(Gom+192, S, t);
  }

  // <X_i> = 2 Re sum conj(s[n_i]) sqrt(n_i+1) s[n_i+1]
  const float w1a = sqrtf((float)(wvu+1));
  const float w1b = sqrtf((float)(wvu+5));
  const float w2 = sqrtf((float)(i2c+1)), w3 = sqrtf((float)(i3c+1));
  float am0=0.f, am1=0.f, am2=0.f, am3=0.f;
#pragma unroll
  for (int e=0;e<16;e++){
    const int idx = e*256 + t;
    const float2 a = S[SW(idx)];
    if ((e>>1) < 7){
      const float2 bz = S[SW(idx+512)];
      am0 = fmaf(a.x*bz.x + a.y*bz.y, sqrtf((float)((e>>1)+1)), am0);
    }
    if (((e&1)==0) || (wvu<3)){          // i1 = wvu + 4*(e&1)
      const float2 bz = S[SW(idx+64)];
      am1 = fmaf(a.x*bz.x + a.y*bz.y, (e&1)?w1b:w1a, am1);
    }
    if (i2c < 7){
      const float2 bz = S[SW(idx+8)];
      am2 = fmaf(a.x*bz.x + a.y*bz.y, w2, am2);
    }
    if (i3c < 7){
      const float2 bz = S[SW(idx+1)];
      am3 = fmaf(a.x*bz.x + a.y*bz.y, w3, am3);
    }
  }
#pragma unroll
  for (int o=32;o;o>>=1){
    am0 += __shfl_down(am0,o,64);
    am1 += __shfl_down(am1,o,64);
    am2 += __shfl_down(am2,o,64);
    am3 += __shfl_down(am3,o,64);
  }
  __syncthreads();                       // all state reads done before red reuses S
  float* red = (float*)S;
  if ((t&63)==0){
    red[wvu*4+0]=am0; red[wvu*4+1]=am1; red[wvu*4+2]=am2; red[wvu*4+3]=am3;
  }
  __syncthreads();
  if (t<4) out[b*4+t] = 2.f*(red[t]+red[4+t]+red[8+t]+red[12+t]);
}

// ---------------- host ----------------
extern "C" void kernel_launch(void* const* d_in, const int* in_sizes, int n_in,
                              void* d_out, int out_size, void* d_ws, size_t ws_size,
                              hipStream_t stream)
{
  const float* x    = (const float*)d_in[0];
  const float* th1  = (const float*)d_in[1];
  const float* ph1  = (const float*)d_in[2];
  const float* vph1 = (const float*)d_in[3];
  const float* rr   = (const float*)d_in[4];
  const float* phr  = (const float*)d_in[5];
  const float* th2  = (const float*)d_in[6];
  const float* ph2  = (const float*)d_in[7];
  const float* vph2 = (const float*)d_in[8];
  const float* aa   = (const float*)d_in[9];
  const float* pha  = (const float*)d_in[10];
  const float* kap  = (const float*)d_in[11];
  float2* ws  = (float2*)d_ws;
  float*  out = (float*)d_out;
  const int B = in_sizes[0] / 4;

  hipLaunchKernelGGL(setup_bs, dim3(24), dim3(256), 0, stream, th1, ph1, th2, ph2, ws);
  hipLaunchKernelGGL(setup_small, dim3(16), dim3(128), 0, stream,
                     rr, phr, aa, pha, vph1, vph2, kap, ws + WS_G1_OFF);
  hipLaunchKernelGGL(qnn_main, dim3(B), dim3(256), 0, stream, x, ws, out);
}